// Round 17
// baseline (666.355 us; speedup 1.0000x reference)
//
#include <hip/hip_runtime.h>

// ConvSNN forward, T=16, B=128. One kernel per LAYER, t-loop inside, LIF state
// in REGISTERS. conv2/conv3/fc1 via MFMA bf16 with TRIPLE-split weights
// (hi+mid+lo ~= fp32 to ~2^-27 rel); activations are pooled spikes, exact bf16.
// B-fragments (t-invariant weights) in REGISTERS.
// THIS ROUND: conv3 restructured to 32-oc blocks with ics-SPLIT waves:
// A-fragment LDS reads (the structural bottleneck: wave-wide b128 = 8 req/bank
// minimum) are halved by halving per-image block duplication; cross-ics partial
// sums exchanged via small LDS buffer. 16 waves/CU (was 8).

typedef __attribute__((ext_vector_type(8))) short bf16x8;
typedef __attribute__((ext_vector_type(4))) float f32x4;

__device__ __forceinline__ unsigned short f2bf(float f) {
  unsigned int u = __float_as_uint(f);
  return (unsigned short)((u + 0x7fffu + ((u >> 16) & 1u)) >> 16);
}
__device__ __forceinline__ float bf2f(unsigned short h) {
  return __uint_as_float(((unsigned int)h) << 16);
}
__device__ __forceinline__ unsigned short split3(float wv, int sp) {
  unsigned short hi = f2bf(wv);
  float r1 = wv - bf2f(hi);
  unsigned short mid = f2bf(r1);
  if (sp == 0) return hi;
  if (sp == 1) return mid;
  return f2bf(r1 - bf2f(mid));
}
__device__ __forceinline__ float lif1(float inp, float vth, float& v, float& i) {
  float vd = fmaf(0.1f, i - v, v);
  float z = (vd > vth) ? 1.0f : 0.0f;
  v = (vd > vth) ? 0.0f : vd;
  i = fmaf(0.8f, i, inp);
  return z;
}
__device__ __forceinline__ f32x4 mfma16(bf16x8 a, bf16x8 b, f32x4 c) {
  return __builtin_amdgcn_mfma_f32_16x16x32_bf16(a, b, c, 0, 0, 0);
}

// ---------- one-time weight split+pack into B-fragment order ----------
// conv2 layout: [ocg 4][sp 3][dydx 9][g 4][ocl 16][j 8]  (ic = 8g+j); 55296
__global__ __launch_bounds__(256) void k_pack2(const float* __restrict__ wc2,
                                               unsigned short* __restrict__ wpk) {
  int idx = blockIdx.x * 256 + threadIdx.x;
  if (idx >= 55296) return;
  int j = idx & 7, ocl = (idx >> 3) & 15, g = (idx >> 7) & 3;
  int r = idx >> 9;                         // 0..107
  int dydx = r % 9; int q = r / 9;          // 0..11
  int sp = q % 3, ocg = q / 3;
  int oc = ocg * 16 + ocl, ic = g * 8 + j;
  wpk[idx] = split3(wc2[(oc * 32 + ic) * 9 + dydx], sp);
}
// conv3 layout: [ocg 8][ics 2][sp 3][dydx 9][g 4][ocl 16][j 8]; 442368
__global__ __launch_bounds__(256) void k_pack3(const float* __restrict__ wc3,
                                               unsigned short* __restrict__ wpk) {
  int idx = blockIdx.x * 256 + threadIdx.x;
  if (idx >= 442368) return;
  int j = idx & 7, ocl = (idx >> 3) & 15, g = (idx >> 7) & 3;
  int r = idx >> 9;
  int dydx = r % 9; int q = r / 9;
  int sp = q % 3; int q2 = q / 3;
  int ics = q2 & 1, ocg = q2 >> 1;
  int oc = ocg * 16 + ocl, ic = ics * 32 + g * 8 + j;
  wpk[idx] = split3(wc3[(oc * 64 + ic) * 9 + dydx], sp);
}

// ---------- conv1 (3->32) fp32, double-buffered LDS, 1 barrier/t ----------
// grid 1024 = b(128) x h(2) x g(4: 8 oc); 256 thr = 128 sites x 2 sub(4 oc each).
__global__ __launch_bounds__(256) void k_conv1(const float* __restrict__ x,
    const float* __restrict__ wc, unsigned short* __restrict__ z1bf)
{
  const int bid = blockIdx.x;
  const int g = bid & 3, h = (bid >> 2) & 1, b = bid >> 3;
  const int tid = threadIdx.x;
  __shared__ float xs[2][3][18][34];           // 2 x 7344 B
  __shared__ __align__(16) float wl[8][28];    // rows padded 27->28
  for (int i = tid; i < 216; i += 256) wl[i / 27][i % 27] = wc[g * 216 + i];
  int ssrc[8];
#pragma unroll
  for (int k2 = 0; k2 < 8; ++k2) {
    int i = tid + k2 * 256;
    int v = -1;
    if (i < 1836) {
      int c = i / 612, rr = i % 612;
      int row = rr / 34, col = rr % 34;
      int gy = h * 16 + row - 1, gx = col - 1;
      if (gy >= 0 && gy < 32 && gx >= 0 && gx < 32) v = c * 1024 + gy * 32 + gx;
    }
    ssrc[k2] = v;
  }
  const int site = tid >> 1, sub = tid & 1;
  const int ph = site >> 4, pw = site & 15;
  const int py = h * 8 + ph;
  float vst[4][4], ist[4][4];
#pragma unroll
  for (int jj = 0; jj < 4; ++jj)
#pragma unroll
    for (int r = 0; r < 4; ++r) { vst[jj][r] = 0.f; ist[jj][r] = 0.f; }

  float vals[8];
  float* xsf0 = &xs[0][0][0][0];
  float* xsf1 = &xs[1][0][0][0];
  {
    const float* xt0 = x + b * 3072;
#pragma unroll
    for (int k2 = 0; k2 < 8; ++k2)
      vals[k2] = (ssrc[k2] >= 0) ? xt0[ssrc[k2]] : 0.f;
#pragma unroll
    for (int k2 = 0; k2 < 8; ++k2) {
      int i = tid + k2 * 256;
      if (i < 1836) xsf0[i] = vals[k2];
    }
    const float* xt1 = x + 393216 + b * 3072;
#pragma unroll
    for (int k2 = 0; k2 < 8; ++k2)
      vals[k2] = (ssrc[k2] >= 0) ? xt1[ssrc[k2]] : 0.f;
  }
  __syncthreads();                             // wl + buf0 staged

  for (int t = 0; t < 16; ++t) {
    float* xw = (t & 1) ? xsf0 : xsf1;         // write target = buf[(t+1)&1]
    const float (*xr)[18][34] = xs[t & 1];     // read buffer
    if (t < 15) {
#pragma unroll
      for (int k2 = 0; k2 < 8; ++k2) {
        int i = tid + k2 * 256;
        if (i < 1836) xw[i] = vals[k2];
      }
    }
    if (t < 14) {
      const float* xt = x + (size_t)(t + 2) * 393216 + b * 3072;
#pragma unroll
      for (int k2 = 0; k2 < 8; ++k2)
        vals[k2] = (ssrc[k2] >= 0) ? xt[ssrc[k2]] : 0.f;
    }
    float p[3][4][4];
#pragma unroll
    for (int c = 0; c < 3; ++c)
#pragma unroll
      for (int r = 0; r < 4; ++r) {
        float2 q0 = *(const float2*)&xr[c][2 * ph + r][2 * pw];
        float2 q1 = *(const float2*)&xr[c][2 * ph + r][2 * pw + 2];
        p[c][r][0] = q0.x; p[c][r][1] = q0.y; p[c][r][2] = q1.x; p[c][r][3] = q1.y;
      }
    unsigned short zout[4];
#pragma unroll
    for (int jj = 0; jj < 4; ++jj) {
      float wreg[28];
      const float4* wrow = (const float4*)&wl[sub * 4 + jj][0];
#pragma unroll
      for (int u = 0; u < 7; ++u) *(float4*)&wreg[u * 4] = wrow[u];
      float s00 = 0, s01 = 0, s10 = 0, s11 = 0;
#pragma unroll
      for (int c = 0; c < 3; ++c)
#pragma unroll
        for (int kh = 0; kh < 3; ++kh)
#pragma unroll
          for (int kw = 0; kw < 3; ++kw) {
            float wvv = wreg[(c * 3 + kh) * 3 + kw];
            s00 = fmaf(p[c][kh][kw],     wvv, s00);
            s01 = fmaf(p[c][kh][kw+1],   wvv, s01);
            s10 = fmaf(p[c][kh+1][kw],   wvv, s10);
            s11 = fmaf(p[c][kh+1][kw+1], wvv, s11);
          }
      float z0 = lif1(s00, 0.25f, vst[jj][0], ist[jj][0]);
      float z1 = lif1(s01, 0.25f, vst[jj][1], ist[jj][1]);
      float z2 = lif1(s10, 0.25f, vst[jj][2], ist[jj][2]);
      float z3 = lif1(s11, 0.25f, vst[jj][3], ist[jj][3]);
      zout[jj] = f2bf(0.25f * (z0 + z1 + z2 + z3));
    }
    *(uint2*)&z1bf[(size_t)t * 1048576 + ((b * 16 + py) * 16 + pw) * 32 + g * 8 + sub * 4]
        = *(uint2*)zout;
    __syncthreads();                           // single barrier per t
  }
}

// ---------- conv2 (32->64) MFMA, B in REGS, double-buffered img, 1 barrier/t ----------
// grid 512 = ocg(4: 16 oc) x b(128); 256 thr = 4 waves.
__global__ __launch_bounds__(256, 2) void k_conv2(const unsigned short* __restrict__ z1bf,
    const unsigned short* __restrict__ wpk, unsigned short* __restrict__ z2bf)
{
  const int ocg = blockIdx.x & 3, b = blockIdx.x >> 2;
  const int tid = threadIdx.x;
  __shared__ __align__(16) unsigned short img[2][18][18][40];   // 2 x 25920 B
  __shared__ __align__(16) unsigned short zpl[4][4][16][18];
  const int w = tid >> 6, l = tid & 63;
  const int lg = l >> 4, ll = l & 15;
  const int ry = ll >> 3, xi = ll & 7;
  bf16x8 bw[3][9];
  {
    const unsigned short* wp = wpk + ocg * 13824;
#pragma unroll
    for (int sp = 0; sp < 3; ++sp)
#pragma unroll
      for (int s9 = 0; s9 < 9; ++s9)
        bw[sp][s9] = *(const bf16x8*)(wp + ((sp * 9 + s9) * 4 + lg) * 128 + ll * 8);
  }
  uint4* imgu4 = (uint4*)&img[0][0][0][0];
  {
    uint4 zz = {0, 0, 0, 0};
    for (int e = tid; e < 1620; e += 256)
      if ((e % 5) == 4) { imgu4[e] = zz; imgu4[1620 + e] = zz; }
  }
  int csrc[6], cdst[6];
#pragma unroll
  for (int k2 = 0; k2 < 6; ++k2) {
    int e = tid + k2 * 256;
    int v = -1, d = 0;
    if (e < 1296) {
      int s = e >> 2, u = e & 3;
      int row = s / 18, col = s % 18;
      int gy = row - 1, gx = col - 1;
      d = s * 5 + u;
      if (gy >= 0 && gy < 16 && gx >= 0 && gx < 16)
        v = ((b * 16 + gy) * 16 + gx) * 32 + u * 8;
    }
    csrc[k2] = v; cdst[k2] = d;
  }
  float vst[2][2][4], ist[2][2][4];
#pragma unroll
  for (int rp = 0; rp < 2; ++rp)
#pragma unroll
    for (int ch = 0; ch < 2; ++ch)
#pragma unroll
      for (int r = 0; r < 4; ++r) { vst[rp][ch][r] = 0.f; ist[rp][ch][r] = 0.f; }

  uint4 vals[6];
  {
#pragma unroll
    for (int k2 = 0; k2 < 6; ++k2) {
      uint4 val = {0, 0, 0, 0};
      if (csrc[k2] >= 0) val = *(const uint4*)(z1bf + csrc[k2]);
      vals[k2] = val;
    }
#pragma unroll
    for (int k2 = 0; k2 < 6; ++k2) {
      int e = tid + k2 * 256;
      if (e < 1296) imgu4[cdst[k2]] = vals[k2];
    }
    const unsigned short* zt1 = z1bf + 1048576;
#pragma unroll
    for (int k2 = 0; k2 < 6; ++k2) {
      uint4 val = {0, 0, 0, 0};
      if (csrc[k2] >= 0) val = *(const uint4*)(zt1 + csrc[k2]);
      vals[k2] = val;
    }
  }
  __syncthreads();                             // buf0 staged

  for (int t = 0; t < 16; ++t) {
    const int cur = t & 1, nxt = cur ^ 1;
    if (t < 15) {
#pragma unroll
      for (int k2 = 0; k2 < 6; ++k2) {
        int e = tid + k2 * 256;
        if (e < 1296) imgu4[nxt * 1620 + cdst[k2]] = vals[k2];
      }
    }
    if (t < 14) {
      const unsigned short* zt = z1bf + (size_t)(t + 2) * 1048576;
#pragma unroll
      for (int k2 = 0; k2 < 6; ++k2) {
        uint4 val = {0, 0, 0, 0};
        if (csrc[k2] >= 0) val = *(const uint4*)(zt + csrc[k2]);
        vals[k2] = val;
      }
    }
    f32x4 acc[2][2] = {};
#pragma unroll
    for (int s9 = 0; s9 < 9; ++s9) {
      const int dy = s9 / 3, dx = s9 % 3;
      bf16x8 a[2][2];
#pragma unroll
      for (int rp = 0; rp < 2; ++rp)
#pragma unroll
        for (int ch = 0; ch < 2; ++ch)
          a[rp][ch] = *(const bf16x8*)&img[cur][4 * w + 2 * rp + ry + dy][ch * 8 + xi + dx][8 * lg];
#pragma unroll
      for (int sp = 0; sp < 3; ++sp)
#pragma unroll
        for (int rp = 0; rp < 2; ++rp)
#pragma unroll
          for (int ch = 0; ch < 2; ++ch)
            acc[rp][ch] = mfma16(a[rp][ch], bw[sp][s9], acc[rp][ch]);
    }
#pragma unroll
    for (int rp = 0; rp < 2; ++rp)
#pragma unroll
      for (int ch = 0; ch < 2; ++ch)
#pragma unroll
        for (int r = 0; r < 4; ++r) {
          int m = 4 * lg + r;
          float z = lif1(acc[rp][ch][r], 0.2f, vst[rp][ch][r], ist[rp][ch][r]);
          zpl[w][2 * rp + (m >> 3)][ch * 8 + (m & 7)][ll] = f2bf(z);
        }
#pragma unroll
    for (int pp = 0; pp < 4; ++pp) {
      int prow = lg >> 1, pcol = (lg & 1) * 4 + pp;
      float zs = bf2f(zpl[w][2*prow][2*pcol][ll])   + bf2f(zpl[w][2*prow][2*pcol+1][ll]) +
                 bf2f(zpl[w][2*prow+1][2*pcol][ll]) + bf2f(zpl[w][2*prow+1][2*pcol+1][ll]);
      z2bf[(size_t)t * 524288 + ((b * 8 + w * 2 + prow) * 8 + pcol) * 64 + ocg * 16 + ll]
          = f2bf(0.25f * zs);
    }
    __syncthreads();                           // single barrier per t
  }
}

// ---------- conv3 (64->128) MFMA, 32-oc blocks, ics-split waves -> z3t[t] ----------
// grid 512 = ocg(4: 32 oc) x b(128); 512 thr = 8 waves = ics(2) x rowpair(4).
// Per wave: 1 ics (K=32), 32 oc (2 tl), 54 B-frags in regs, 9 A-reads/t.
// Cross-ics partial sums exchanged via xchg LDS; epilogue on ics==0 waves.
__global__ __launch_bounds__(512, 4) void k_conv3(const unsigned short* __restrict__ z2bf,
    const unsigned short* __restrict__ wpk, unsigned short* __restrict__ z3t)
{
  const int ocg = blockIdx.x & 3, b = blockIdx.x >> 2;
  const int tid = threadIdx.x;
  __shared__ __align__(16) unsigned short img[2][10][12][72];   // 34560 B
  __shared__ __align__(16) unsigned short zpl[4][16][34];       // 4352 B
  __shared__ __align__(16) float xchg[4][2][64][4];             // 8192 B
  const int w = tid >> 6, l = tid & 63;
  const int ics = w & 1, rp = w >> 1;
  const int lg = l >> 4, ll = l & 15;
  const int ry = ll >> 3, xi = ll & 7;
  // B fragments in registers (t-invariant): [tl][sp][s9] for this wave's ics
  bf16x8 bw[2][3][9];
#pragma unroll
  for (int tl = 0; tl < 2; ++tl) {
    const unsigned short* wp = wpk + (ocg * 2 + tl) * 27648 + ics * 13824;
#pragma unroll
    for (int sp = 0; sp < 3; ++sp)
#pragma unroll
      for (int s9 = 0; s9 < 9; ++s9)
        bw[tl][sp][s9] = *(const bf16x8*)(wp + ((sp * 9 + s9) * 4 + lg) * 128 + ll * 8);
  }
  uint4* imgu4 = (uint4*)&img[0][0][0][0];
  {
    uint4 zz = {0, 0, 0, 0};
    for (int e = tid; e < 1080; e += 512)
      if ((e % 9) == 8) { imgu4[e] = zz; imgu4[1080 + e] = zz; }
  }
  int csrc[2], cdst[2];
#pragma unroll
  for (int k2 = 0; k2 < 2; ++k2) {
    int e = tid + k2 * 512;
    int v = -1, d = 0;
    if (e < 960) {
      int s = e >> 3, u = e & 7;
      int row = s / 12, col = s % 12;
      int gy = row - 1, gx = col - 1;
      d = s * 9 + u;
      if (gy >= 0 && gy < 8 && gx >= 0 && gx < 8)
        v = ((b * 8 + gy) * 8 + gx) * 64 + u * 8;
    }
    csrc[k2] = v; cdst[k2] = d;
  }
  float vst[2][4], ist[2][4];
#pragma unroll
  for (int tl = 0; tl < 2; ++tl)
#pragma unroll
    for (int r = 0; r < 4; ++r) { vst[tl][r] = 0.f; ist[tl][r] = 0.f; }

  uint4 vals[2];
  {
#pragma unroll
    for (int k2 = 0; k2 < 2; ++k2) {
      uint4 val = {0, 0, 0, 0};
      if (csrc[k2] >= 0) val = *(const uint4*)(z2bf + csrc[k2]);
      vals[k2] = val;
    }
#pragma unroll
    for (int k2 = 0; k2 < 2; ++k2) {
      int e = tid + k2 * 512;
      if (e < 960) imgu4[cdst[k2]] = vals[k2];
    }
    const unsigned short* zt1 = z2bf + 524288;
#pragma unroll
    for (int k2 = 0; k2 < 2; ++k2) {
      uint4 val = {0, 0, 0, 0};
      if (csrc[k2] >= 0) val = *(const uint4*)(zt1 + csrc[k2]);
      vals[k2] = val;
    }
  }
  __syncthreads();                             // buf0 staged

  for (int t = 0; t < 16; ++t) {
    const int cur = t & 1, nxt = cur ^ 1;
    if (t < 15) {
#pragma unroll
      for (int k2 = 0; k2 < 2; ++k2) {
        int e = tid + k2 * 512;
        if (e < 960) imgu4[nxt * 1080 + cdst[k2]] = vals[k2];
      }
    }
    if (t < 14) {
      const unsigned short* zt = z2bf + (size_t)(t + 2) * 524288;
#pragma unroll
      for (int k2 = 0; k2 < 2; ++k2) {
        uint4 val = {0, 0, 0, 0};
        if (csrc[k2] >= 0) val = *(const uint4*)(zt + csrc[k2]);
        vals[k2] = val;
      }
    }
    f32x4 acc[2] = {};
#pragma unroll
    for (int s9 = 0; s9 < 9; ++s9) {
      const int dy = s9 / 3, dx = s9 % 3;
      bf16x8 a = *(const bf16x8*)&img[cur][2 * rp + ry + dy][xi + dx][ics * 32 + 8 * lg];
#pragma unroll
      for (int tl = 0; tl < 2; ++tl)
#pragma unroll
        for (int sp = 0; sp < 3; ++sp)
          acc[tl] = mfma16(a, bw[tl][sp][s9], acc[tl]);
    }
    if (ics == 1) {
#pragma unroll
      for (int tl = 0; tl < 2; ++tl)
        *(f32x4*)&xchg[rp][tl][l][0] = acc[tl];
    }
    __syncthreads();                           // xchg ready
    if (ics == 0) {
#pragma unroll
      for (int tl = 0; tl < 2; ++tl) {
        f32x4 o = *(const f32x4*)&xchg[rp][tl][l][0];
#pragma unroll
        for (int r = 0; r < 4; ++r) {
          float aa = acc[tl][r] + o[r];
          int px = 4 * lg + r;
          float z = lif1(aa, 0.1f, vst[tl][r], ist[tl][r]);
          zpl[rp][px][tl * 16 + ll] = f2bf(z);
        }
      }
#pragma unroll
      for (int tl = 0; tl < 2; ++tl) {
        int oc = tl * 16 + ll;
        float zsum = bf2f(zpl[rp][2*lg][oc])   + bf2f(zpl[rp][2*lg+1][oc]) +
                     bf2f(zpl[rp][8+2*lg][oc]) + bf2f(zpl[rp][9+2*lg][oc]);
        z3t[(size_t)t * 262144 + b * 2048 + (ocg * 32 + oc) * 16 + rp * 4 + lg]
            = f2bf(0.25f * zsum);
      }
    }
    __syncthreads();                           // img[cur] fully read; xchg consumed
  }
}

// ---------- fc1 (2048->1024) MFMA, K-split 8, B in REGS (24 frags) ----------
// grid 1024 = kb8 x nb64(16 n) x bb2; 256 thr = 4 waves (bt). LDS = 32 KB slab only.
__global__ __launch_bounds__(256) void k_fc1(const unsigned short* __restrict__ z3t,
    const float* __restrict__ wf1, float* __restrict__ P1)
{
  const int bid = blockIdx.x;
  const int kb = bid & 7, nb = (bid >> 3) & 63, bb = bid >> 9;
  const int tid = threadIdx.x;
  __shared__ __align__(16) unsigned short slab[16384];  // wl3 staging first, then A-slab
  for (int i = tid; i < 4096; i += 256) {
    int n = i >> 8, k = i & 255;
    float wv = wf1[(size_t)(nb * 16 + n) * 2048 + kb * 256 + k];
    unsigned short hi = f2bf(wv);
    float r1 = wv - bf2f(hi);
    unsigned short mid = f2bf(r1);
    unsigned short lo = f2bf(r1 - bf2f(mid));
    int off = ((k >> 5) * 4 + ((k >> 3) & 3)) * 128 + n * 8 + (k & 7);
    slab[off] = hi; slab[4096 + off] = mid; slab[8192 + off] = lo;
  }
  __syncthreads();
  const int w = tid >> 6, l = tid & 63;
  const int lg = l >> 4, ll = l & 15;
  bf16x8 bwf[8][3];
#pragma unroll
  for (int ks = 0; ks < 8; ++ks)
#pragma unroll
    for (int sp = 0; sp < 3; ++sp)
      bwf[ks][sp] = *(const bf16x8*)&slab[sp * 4096 + (ks * 4 + lg) * 128 + ll * 8];
  const int arow = w * 16 + ll;
  const int bo = bb * 64 + w * 16;

  for (int t = 0; t < 16; ++t) {
    __syncthreads();                      // prior readers of slab done
    for (int gidx = tid; gidx < 2048; gidx += 256) {
      int row = gidx >> 5, gc = gidx & 31;
      const uint4* s = (const uint4*)(z3t + (size_t)t * 262144 +
                                      ((bb * 64 + row) * 2048 + kb * 256 + gc * 8));
      ((uint4*)slab)[row * 32 + (gc ^ (row & 7))] = *s;
    }
    __syncthreads();
    f32x4 acc = {};
#pragma unroll
    for (int ks = 0; ks < 8; ++ks) {
      bf16x8 a = *(const bf16x8*)&slab[(arow * 32 + ((ks * 4 + lg) ^ (arow & 7))) * 8];
#pragma unroll
      for (int sp = 0; sp < 3; ++sp)
        acc = mfma16(a, bwf[ks][sp], acc);
    }
    float* Pt = P1 + (size_t)t * 1048576 + (size_t)kb * 131072;
#pragma unroll
    for (int r = 0; r < 4; ++r)
      Pt[(bo + 4 * lg + r) * 1024 + nb * 16 + ll] = acc[r];
  }
}

// ---------- fc1 reduce + LIF(0.1), t-loop, state in regs -> z4bf[t][b][n] ----------
__global__ __launch_bounds__(256) void k_fc1b(const float* __restrict__ P1,
    unsigned short* __restrict__ z4bf)
{
  const int site = blockIdx.x * 256 + threadIdx.x;   // 131072 = b*1024+n
  float v = 0.f, ii = 0.f;
  for (int t = 0; t < 16; ++t) {
    const float* p = P1 + (size_t)t * 1048576 + site;
    float a = 0.f;
#pragma unroll
    for (int kb = 0; kb < 8; ++kb) a += p[(size_t)kb * 131072];
    float z = lif1(a, 0.1f, v, ii);
    z4bf[(size_t)t * 131072 + site] = f2bf(z);
  }
}

// ---------- out layer (1024->10) + LI + running max, t-loop, state in regs ----------
__global__ __launch_bounds__(256) void k_out(const unsigned short* __restrict__ z4bf,
    const float* __restrict__ wo, float* __restrict__ out)
{
  const int w = threadIdx.x >> 6, l = threadIdx.x & 63;
  const int b = blockIdx.x * 4 + w;
  float vo[10], io[10], om[10];
#pragma unroll
  for (int o = 0; o < 10; ++o) { vo[o] = 0.f; io[o] = 0.f; om[o] = 0.f; }
  for (int t = 0; t < 16; ++t) {
    float dot[10];
#pragma unroll
    for (int o = 0; o < 10; ++o) dot[o] = 0.f;
    for (int c = 0; c < 16; ++c) {
      const int n = c * 64 + l;
      float z = bf2f(z4bf[(size_t)t * 131072 + b * 1024 + n]);
#pragma unroll
      for (int o = 0; o < 10; ++o) dot[o] = fmaf(z, wo[o * 1024 + n], dot[o]);
    }
#pragma unroll
    for (int o = 0; o < 10; ++o)
#pragma unroll
      for (int d = 32; d > 0; d >>= 1) dot[o] += __shfl_down(dot[o], d);
    if (l == 0) {
#pragma unroll
      for (int o = 0; o < 10; ++o) {
        float vn = fmaf(0.1f, io[o] - vo[o], vo[o]);
        io[o] = fmaf(0.8f, io[o], dot[o]);
        vo[o] = vn;
        om[o] = (t == 0) ? vn : fmaxf(om[o], vn);
      }
    }
  }
  if (l == 0) {
#pragma unroll
    for (int o = 0; o < 10; ++o) out[b * 10 + o] = om[o];
  }
}

extern "C" void kernel_launch(void* const* d_in, const int* in_sizes, int n_in,
                              void* d_out, int out_size, void* d_ws, size_t ws_size,
                              hipStream_t stream)
{
  const float* x   = (const float*)d_in[0];   // (16,128,3,32,32)
  const float* wc1 = (const float*)d_in[1];   // (32,3,3,3)
  const float* wc2 = (const float*)d_in[2];   // (64,32,3,3)
  const float* wc3 = (const float*)d_in[3];   // (128,64,3,3)
  const float* wf1 = (const float*)d_in[4];   // (1024,2048)
  const float* wo  = (const float*)d_in[5];   // (10,1024)
  float* out = (float*)d_out;                 // (128,10)
  char* ws = (char*)d_ws;

  unsigned short* z1bf = (unsigned short*)(ws + 0);          // [16][128,16,16,32]
  unsigned short* z2bf = (unsigned short*)(ws + 33554432);   // [16][128,8,8,64]
  unsigned short* z3t  = (unsigned short*)(ws + 50331648);   // [16][128,2048]
  unsigned short* z4bf = (unsigned short*)(ws + 58720256);   // [16][128,1024]
  float* P1            = (float*)(ws + 62914560);            // [16][8][131072]
  unsigned short* wc2pk = (unsigned short*)(ws + 130023424);
  unsigned short* wc3pk = (unsigned short*)(ws + 130134016);

  k_pack2<<<216, 256, 0, stream>>>(wc2, wc2pk);
  k_pack3<<<1728, 256, 0, stream>>>(wc3, wc3pk);

  k_conv1<<<1024, 256, 0, stream>>>(x, wc1, z1bf);
  k_conv2<<<512, 256, 0, stream>>>(z1bf, wc2pk, z2bf);
  k_conv3<<<512, 512, 0, stream>>>(z2bf, wc3pk, z3t);
  k_fc1 <<<1024, 256, 0, stream>>>(z3t, wf1, P1);
  k_fc1b<<<512, 256, 0, stream>>>(P1, z4bf);
  k_out <<<32, 256, 0, stream>>>(z4bf, wo, out);
}

// Round 18
// 369.726 us; speedup vs baseline: 1.8023x; 1.8023x over previous
//
#include <hip/hip_runtime.h>

// ConvSNN forward, T=16, B=128. One kernel per LAYER, t-loop inside, LIF state
// in REGISTERS. conv2/conv3/fc1 via MFMA bf16 with TRIPLE-split weights
// (hi+mid+lo ~= fp32 to ~2^-27 rel); activations are pooled spikes, exact bf16.
// B-fragments (t-invariant weights) in REGISTERS.
// THIS ROUND: conv3 reverted to r16 structure (r17's ics-split + forced
// occupancy bound spilled 216 B-frag regs to scratch: VGPR capped 64, 1.4 GB
// fetch). One layout fix: img inner dim padded 72->80 shorts (row stride
// 160B = 8 banks mod 32, was 144B = 4) -> A-read bank conflicts ~2-way max.

typedef __attribute__((ext_vector_type(8))) short bf16x8;
typedef __attribute__((ext_vector_type(4))) float f32x4;

__device__ __forceinline__ unsigned short f2bf(float f) {
  unsigned int u = __float_as_uint(f);
  return (unsigned short)((u + 0x7fffu + ((u >> 16) & 1u)) >> 16);
}
__device__ __forceinline__ float bf2f(unsigned short h) {
  return __uint_as_float(((unsigned int)h) << 16);
}
__device__ __forceinline__ unsigned short split3(float wv, int sp) {
  unsigned short hi = f2bf(wv);
  float r1 = wv - bf2f(hi);
  unsigned short mid = f2bf(r1);
  if (sp == 0) return hi;
  if (sp == 1) return mid;
  return f2bf(r1 - bf2f(mid));
}
__device__ __forceinline__ float lif1(float inp, float vth, float& v, float& i) {
  float vd = fmaf(0.1f, i - v, v);
  float z = (vd > vth) ? 1.0f : 0.0f;
  v = (vd > vth) ? 0.0f : vd;
  i = fmaf(0.8f, i, inp);
  return z;
}
__device__ __forceinline__ f32x4 mfma16(bf16x8 a, bf16x8 b, f32x4 c) {
  return __builtin_amdgcn_mfma_f32_16x16x32_bf16(a, b, c, 0, 0, 0);
}

// ---------- one-time weight split+pack into B-fragment order ----------
// conv2 layout: [ocg 4][sp 3][dydx 9][g 4][ocl 16][j 8]  (ic = 8g+j); 55296
__global__ __launch_bounds__(256) void k_pack2(const float* __restrict__ wc2,
                                               unsigned short* __restrict__ wpk) {
  int idx = blockIdx.x * 256 + threadIdx.x;
  if (idx >= 55296) return;
  int j = idx & 7, ocl = (idx >> 3) & 15, g = (idx >> 7) & 3;
  int r = idx >> 9;                         // 0..107
  int dydx = r % 9; int q = r / 9;          // 0..11
  int sp = q % 3, ocg = q / 3;
  int oc = ocg * 16 + ocl, ic = g * 8 + j;
  wpk[idx] = split3(wc2[(oc * 32 + ic) * 9 + dydx], sp);
}
// conv3 layout: [ocg 8][ics 2][sp 3][dydx 9][g 4][ocl 16][j 8]; 442368
__global__ __launch_bounds__(256) void k_pack3(const float* __restrict__ wc3,
                                               unsigned short* __restrict__ wpk) {
  int idx = blockIdx.x * 256 + threadIdx.x;
  if (idx >= 442368) return;
  int j = idx & 7, ocl = (idx >> 3) & 15, g = (idx >> 7) & 3;
  int r = idx >> 9;
  int dydx = r % 9; int q = r / 9;
  int sp = q % 3; int q2 = q / 3;
  int ics = q2 & 1, ocg = q2 >> 1;
  int oc = ocg * 16 + ocl, ic = ics * 32 + g * 8 + j;
  wpk[idx] = split3(wc3[(oc * 64 + ic) * 9 + dydx], sp);
}

// ---------- conv1 (3->32) fp32, double-buffered LDS, 1 barrier/t ----------
// grid 1024 = b(128) x h(2) x g(4: 8 oc); 256 thr = 128 sites x 2 sub(4 oc each).
__global__ __launch_bounds__(256) void k_conv1(const float* __restrict__ x,
    const float* __restrict__ wc, unsigned short* __restrict__ z1bf)
{
  const int bid = blockIdx.x;
  const int g = bid & 3, h = (bid >> 2) & 1, b = bid >> 3;
  const int tid = threadIdx.x;
  __shared__ float xs[2][3][18][34];           // 2 x 7344 B
  __shared__ __align__(16) float wl[8][28];    // rows padded 27->28
  for (int i = tid; i < 216; i += 256) wl[i / 27][i % 27] = wc[g * 216 + i];
  int ssrc[8];
#pragma unroll
  for (int k2 = 0; k2 < 8; ++k2) {
    int i = tid + k2 * 256;
    int v = -1;
    if (i < 1836) {
      int c = i / 612, rr = i % 612;
      int row = rr / 34, col = rr % 34;
      int gy = h * 16 + row - 1, gx = col - 1;
      if (gy >= 0 && gy < 32 && gx >= 0 && gx < 32) v = c * 1024 + gy * 32 + gx;
    }
    ssrc[k2] = v;
  }
  const int site = tid >> 1, sub = tid & 1;
  const int ph = site >> 4, pw = site & 15;
  const int py = h * 8 + ph;
  float vst[4][4], ist[4][4];
#pragma unroll
  for (int jj = 0; jj < 4; ++jj)
#pragma unroll
    for (int r = 0; r < 4; ++r) { vst[jj][r] = 0.f; ist[jj][r] = 0.f; }

  float vals[8];
  float* xsf0 = &xs[0][0][0][0];
  float* xsf1 = &xs[1][0][0][0];
  {
    const float* xt0 = x + b * 3072;
#pragma unroll
    for (int k2 = 0; k2 < 8; ++k2)
      vals[k2] = (ssrc[k2] >= 0) ? xt0[ssrc[k2]] : 0.f;
#pragma unroll
    for (int k2 = 0; k2 < 8; ++k2) {
      int i = tid + k2 * 256;
      if (i < 1836) xsf0[i] = vals[k2];
    }
    const float* xt1 = x + 393216 + b * 3072;
#pragma unroll
    for (int k2 = 0; k2 < 8; ++k2)
      vals[k2] = (ssrc[k2] >= 0) ? xt1[ssrc[k2]] : 0.f;
  }
  __syncthreads();                             // wl + buf0 staged

  for (int t = 0; t < 16; ++t) {
    float* xw = (t & 1) ? xsf0 : xsf1;         // write target = buf[(t+1)&1]
    const float (*xr)[18][34] = xs[t & 1];     // read buffer
    if (t < 15) {
#pragma unroll
      for (int k2 = 0; k2 < 8; ++k2) {
        int i = tid + k2 * 256;
        if (i < 1836) xw[i] = vals[k2];
      }
    }
    if (t < 14) {
      const float* xt = x + (size_t)(t + 2) * 393216 + b * 3072;
#pragma unroll
      for (int k2 = 0; k2 < 8; ++k2)
        vals[k2] = (ssrc[k2] >= 0) ? xt[ssrc[k2]] : 0.f;
    }
    float p[3][4][4];
#pragma unroll
    for (int c = 0; c < 3; ++c)
#pragma unroll
      for (int r = 0; r < 4; ++r) {
        float2 q0 = *(const float2*)&xr[c][2 * ph + r][2 * pw];
        float2 q1 = *(const float2*)&xr[c][2 * ph + r][2 * pw + 2];
        p[c][r][0] = q0.x; p[c][r][1] = q0.y; p[c][r][2] = q1.x; p[c][r][3] = q1.y;
      }
    unsigned short zout[4];
#pragma unroll
    for (int jj = 0; jj < 4; ++jj) {
      float wreg[28];
      const float4* wrow = (const float4*)&wl[sub * 4 + jj][0];
#pragma unroll
      for (int u = 0; u < 7; ++u) *(float4*)&wreg[u * 4] = wrow[u];
      float s00 = 0, s01 = 0, s10 = 0, s11 = 0;
#pragma unroll
      for (int c = 0; c < 3; ++c)
#pragma unroll
        for (int kh = 0; kh < 3; ++kh)
#pragma unroll
          for (int kw = 0; kw < 3; ++kw) {
            float wvv = wreg[(c * 3 + kh) * 3 + kw];
            s00 = fmaf(p[c][kh][kw],     wvv, s00);
            s01 = fmaf(p[c][kh][kw+1],   wvv, s01);
            s10 = fmaf(p[c][kh+1][kw],   wvv, s10);
            s11 = fmaf(p[c][kh+1][kw+1], wvv, s11);
          }
      float z0 = lif1(s00, 0.25f, vst[jj][0], ist[jj][0]);
      float z1 = lif1(s01, 0.25f, vst[jj][1], ist[jj][1]);
      float z2 = lif1(s10, 0.25f, vst[jj][2], ist[jj][2]);
      float z3 = lif1(s11, 0.25f, vst[jj][3], ist[jj][3]);
      zout[jj] = f2bf(0.25f * (z0 + z1 + z2 + z3));
    }
    *(uint2*)&z1bf[(size_t)t * 1048576 + ((b * 16 + py) * 16 + pw) * 32 + g * 8 + sub * 4]
        = *(uint2*)zout;
    __syncthreads();                           // single barrier per t
  }
}

// ---------- conv2 (32->64) MFMA, B in REGS, double-buffered img, 1 barrier/t ----------
// grid 512 = ocg(4: 16 oc) x b(128); 256 thr = 4 waves.
__global__ __launch_bounds__(256, 2) void k_conv2(const unsigned short* __restrict__ z1bf,
    const unsigned short* __restrict__ wpk, unsigned short* __restrict__ z2bf)
{
  const int ocg = blockIdx.x & 3, b = blockIdx.x >> 2;
  const int tid = threadIdx.x;
  __shared__ __align__(16) unsigned short img[2][18][18][40];   // 2 x 25920 B
  __shared__ __align__(16) unsigned short zpl[4][4][16][18];
  const int w = tid >> 6, l = tid & 63;
  const int lg = l >> 4, ll = l & 15;
  const int ry = ll >> 3, xi = ll & 7;
  bf16x8 bw[3][9];
  {
    const unsigned short* wp = wpk + ocg * 13824;
#pragma unroll
    for (int sp = 0; sp < 3; ++sp)
#pragma unroll
      for (int s9 = 0; s9 < 9; ++s9)
        bw[sp][s9] = *(const bf16x8*)(wp + ((sp * 9 + s9) * 4 + lg) * 128 + ll * 8);
  }
  uint4* imgu4 = (uint4*)&img[0][0][0][0];
  {
    uint4 zz = {0, 0, 0, 0};
    for (int e = tid; e < 1620; e += 256)
      if ((e % 5) == 4) { imgu4[e] = zz; imgu4[1620 + e] = zz; }
  }
  int csrc[6], cdst[6];
#pragma unroll
  for (int k2 = 0; k2 < 6; ++k2) {
    int e = tid + k2 * 256;
    int v = -1, d = 0;
    if (e < 1296) {
      int s = e >> 2, u = e & 3;
      int row = s / 18, col = s % 18;
      int gy = row - 1, gx = col - 1;
      d = s * 5 + u;
      if (gy >= 0 && gy < 16 && gx >= 0 && gx < 16)
        v = ((b * 16 + gy) * 16 + gx) * 32 + u * 8;
    }
    csrc[k2] = v; cdst[k2] = d;
  }
  float vst[2][2][4], ist[2][2][4];
#pragma unroll
  for (int rp = 0; rp < 2; ++rp)
#pragma unroll
    for (int ch = 0; ch < 2; ++ch)
#pragma unroll
      for (int r = 0; r < 4; ++r) { vst[rp][ch][r] = 0.f; ist[rp][ch][r] = 0.f; }

  uint4 vals[6];
  {
#pragma unroll
    for (int k2 = 0; k2 < 6; ++k2) {
      uint4 val = {0, 0, 0, 0};
      if (csrc[k2] >= 0) val = *(const uint4*)(z1bf + csrc[k2]);
      vals[k2] = val;
    }
#pragma unroll
    for (int k2 = 0; k2 < 6; ++k2) {
      int e = tid + k2 * 256;
      if (e < 1296) imgu4[cdst[k2]] = vals[k2];
    }
    const unsigned short* zt1 = z1bf + 1048576;
#pragma unroll
    for (int k2 = 0; k2 < 6; ++k2) {
      uint4 val = {0, 0, 0, 0};
      if (csrc[k2] >= 0) val = *(const uint4*)(zt1 + csrc[k2]);
      vals[k2] = val;
    }
  }
  __syncthreads();                             // buf0 staged

  for (int t = 0; t < 16; ++t) {
    const int cur = t & 1, nxt = cur ^ 1;
    if (t < 15) {
#pragma unroll
      for (int k2 = 0; k2 < 6; ++k2) {
        int e = tid + k2 * 256;
        if (e < 1296) imgu4[nxt * 1620 + cdst[k2]] = vals[k2];
      }
    }
    if (t < 14) {
      const unsigned short* zt = z1bf + (size_t)(t + 2) * 1048576;
#pragma unroll
      for (int k2 = 0; k2 < 6; ++k2) {
        uint4 val = {0, 0, 0, 0};
        if (csrc[k2] >= 0) val = *(const uint4*)(zt + csrc[k2]);
        vals[k2] = val;
      }
    }
    f32x4 acc[2][2] = {};
#pragma unroll
    for (int s9 = 0; s9 < 9; ++s9) {
      const int dy = s9 / 3, dx = s9 % 3;
      bf16x8 a[2][2];
#pragma unroll
      for (int rp = 0; rp < 2; ++rp)
#pragma unroll
        for (int ch = 0; ch < 2; ++ch)
          a[rp][ch] = *(const bf16x8*)&img[cur][4 * w + 2 * rp + ry + dy][ch * 8 + xi + dx][8 * lg];
#pragma unroll
      for (int sp = 0; sp < 3; ++sp)
#pragma unroll
        for (int rp = 0; rp < 2; ++rp)
#pragma unroll
          for (int ch = 0; ch < 2; ++ch)
            acc[rp][ch] = mfma16(a[rp][ch], bw[sp][s9], acc[rp][ch]);
    }
#pragma unroll
    for (int rp = 0; rp < 2; ++rp)
#pragma unroll
      for (int ch = 0; ch < 2; ++ch)
#pragma unroll
        for (int r = 0; r < 4; ++r) {
          int m = 4 * lg + r;
          float z = lif1(acc[rp][ch][r], 0.2f, vst[rp][ch][r], ist[rp][ch][r]);
          zpl[w][2 * rp + (m >> 3)][ch * 8 + (m & 7)][ll] = f2bf(z);
        }
#pragma unroll
    for (int pp = 0; pp < 4; ++pp) {
      int prow = lg >> 1, pcol = (lg & 1) * 4 + pp;
      float zs = bf2f(zpl[w][2*prow][2*pcol][ll])   + bf2f(zpl[w][2*prow][2*pcol+1][ll]) +
                 bf2f(zpl[w][2*prow+1][2*pcol][ll]) + bf2f(zpl[w][2*prow+1][2*pcol+1][ll]);
      z2bf[(size_t)t * 524288 + ((b * 8 + w * 2 + prow) * 8 + pcol) * 64 + ocg * 16 + ll]
          = f2bf(0.25f * zs);
    }
    __syncthreads();                           // single barrier per t
  }
}

// ---------- conv3 (64->128) MFMA full-K, B in REGS, dbuf img (pad 80), 1 barrier/t ----------
// grid 1024 = ocg(8: 16 oc) x b(128); 256 thr = 4 waves (row-pairs).
// img inner dim 80 shorts (160B row stride = 8 banks mod 32): A-read conflicts ~2-way.
__global__ __launch_bounds__(256, 2) void k_conv3(const unsigned short* __restrict__ z2bf,
    const unsigned short* __restrict__ wpk, unsigned short* __restrict__ z3t)
{
  const int bid = blockIdx.x;
  const int ocg = bid & 7, b = bid >> 3;
  const int tid = threadIdx.x;
  __shared__ __align__(16) unsigned short img[2][10][12][80];   // 2 x 19200 B
  __shared__ __align__(16) unsigned short zpl[4][16][18];
  const int w = tid >> 6, l = tid & 63;
  const int lg = l >> 4, ll = l & 15;
  const int ry = ll >> 3, xi = ll & 7;
  bf16x8 bw[2][3][9];
  {
    const unsigned short* wp = wpk + ocg * 27648;
#pragma unroll
    for (int ics = 0; ics < 2; ++ics)
#pragma unroll
      for (int sp = 0; sp < 3; ++sp)
#pragma unroll
        for (int s9 = 0; s9 < 9; ++s9)
          bw[ics][sp][s9] = *(const bf16x8*)(wp + ics * 13824 +
                                             ((sp * 9 + s9) * 4 + lg) * 128 + ll * 8);
  }
  uint4* imgu4 = (uint4*)&img[0][0][0][0];
  // cell = 10 u4 (8 data + 2 pad). pad written once for both buffers.
  {
    uint4 zz = {0, 0, 0, 0};
    for (int e = tid; e < 1200; e += 256) {
      int u = e % 10;
      if (u >= 8) { imgu4[e] = zz; imgu4[1200 + e] = zz; }
    }
  }
  int csrc[4], cdst[4];
#pragma unroll
  for (int k2 = 0; k2 < 4; ++k2) {
    int e = tid + k2 * 256;
    int v = -1, d = 0;
    {
      int s = e >> 3, u = e & 7;          // e < 960: 120 cells x 8 data u4
      int row = s / 12, col = s % 12;
      int gy = row - 1, gx = col - 1;
      d = s * 10 + u;
      if (gy >= 0 && gy < 8 && gx >= 0 && gx < 8)
        v = ((b * 8 + gy) * 8 + gx) * 64 + u * 8;
    }
    csrc[k2] = v; cdst[k2] = d;
  }
  float vst[4], ist[4];
#pragma unroll
  for (int r = 0; r < 4; ++r) { vst[r] = 0.f; ist[r] = 0.f; }

  uint4 vals[4];
  {
#pragma unroll
    for (int k2 = 0; k2 < 4; ++k2) {
      uint4 val = {0, 0, 0, 0};
      if (csrc[k2] >= 0) val = *(const uint4*)(z2bf + csrc[k2]);
      vals[k2] = val;
    }
#pragma unroll
    for (int k2 = 0; k2 < 4; ++k2)
      imgu4[cdst[k2]] = vals[k2];
    const unsigned short* zt1 = z2bf + 524288;
#pragma unroll
    for (int k2 = 0; k2 < 4; ++k2) {
      uint4 val = {0, 0, 0, 0};
      if (csrc[k2] >= 0) val = *(const uint4*)(zt1 + csrc[k2]);
      vals[k2] = val;
    }
  }
  __syncthreads();                             // buf0 staged

  for (int t = 0; t < 16; ++t) {
    const int cur = t & 1, nxt = cur ^ 1;
    if (t < 15) {
#pragma unroll
      for (int k2 = 0; k2 < 4; ++k2)
        imgu4[nxt * 1200 + cdst[k2]] = vals[k2];
    }
    if (t < 14) {
      const unsigned short* zt = z2bf + (size_t)(t + 2) * 524288;
#pragma unroll
      for (int k2 = 0; k2 < 4; ++k2) {
        uint4 val = {0, 0, 0, 0};
        if (csrc[k2] >= 0) val = *(const uint4*)(zt + csrc[k2]);
        vals[k2] = val;
      }
    }
    f32x4 acc = {};
#pragma unroll
    for (int ics = 0; ics < 2; ++ics)
#pragma unroll
      for (int s9 = 0; s9 < 9; ++s9) {
        const int dy = s9 / 3, dx = s9 % 3;
        bf16x8 a = *(const bf16x8*)&img[cur][2 * w + ry + dy][xi + dx][ics * 32 + 8 * lg];
#pragma unroll
        for (int sp = 0; sp < 3; ++sp)
          acc = mfma16(a, bw[ics][sp][s9], acc);
      }
#pragma unroll
    for (int r = 0; r < 4; ++r) {
      int px = 4 * lg + r;
      float z = lif1(acc[r], 0.1f, vst[r], ist[r]);
      zpl[w][px][ll] = f2bf(z);
    }
    float zsum = bf2f(zpl[w][2*lg][ll])   + bf2f(zpl[w][2*lg+1][ll]) +
                 bf2f(zpl[w][8+2*lg][ll]) + bf2f(zpl[w][9+2*lg][ll]);
    z3t[(size_t)t * 262144 + b * 2048 + (ocg * 16 + ll) * 16 + w * 4 + lg]
        = f2bf(0.25f * zsum);
    __syncthreads();                           // single barrier per t
  }
}

// ---------- fc1 (2048->1024) MFMA, K-split 8, B in REGS (24 frags) ----------
// grid 1024 = kb8 x nb64(16 n) x bb2; 256 thr = 4 waves (bt). LDS = 32 KB slab only.
__global__ __launch_bounds__(256) void k_fc1(const unsigned short* __restrict__ z3t,
    const float* __restrict__ wf1, float* __restrict__ P1)
{
  const int bid = blockIdx.x;
  const int kb = bid & 7, nb = (bid >> 3) & 63, bb = bid >> 9;
  const int tid = threadIdx.x;
  __shared__ __align__(16) unsigned short slab[16384];  // wl3 staging first, then A-slab
  for (int i = tid; i < 4096; i += 256) {
    int n = i >> 8, k = i & 255;
    float wv = wf1[(size_t)(nb * 16 + n) * 2048 + kb * 256 + k];
    unsigned short hi = f2bf(wv);
    float r1 = wv - bf2f(hi);
    unsigned short mid = f2bf(r1);
    unsigned short lo = f2bf(r1 - bf2f(mid));
    int off = ((k >> 5) * 4 + ((k >> 3) & 3)) * 128 + n * 8 + (k & 7);
    slab[off] = hi; slab[4096 + off] = mid; slab[8192 + off] = lo;
  }
  __syncthreads();
  const int w = tid >> 6, l = tid & 63;
  const int lg = l >> 4, ll = l & 15;
  bf16x8 bwf[8][3];
#pragma unroll
  for (int ks = 0; ks < 8; ++ks)
#pragma unroll
    for (int sp = 0; sp < 3; ++sp)
      bwf[ks][sp] = *(const bf16x8*)&slab[sp * 4096 + (ks * 4 + lg) * 128 + ll * 8];
  const int arow = w * 16 + ll;
  const int bo = bb * 64 + w * 16;

  for (int t = 0; t < 16; ++t) {
    __syncthreads();                      // prior readers of slab done
    for (int gidx = tid; gidx < 2048; gidx += 256) {
      int row = gidx >> 5, gc = gidx & 31;
      const uint4* s = (const uint4*)(z3t + (size_t)t * 262144 +
                                      ((bb * 64 + row) * 2048 + kb * 256 + gc * 8));
      ((uint4*)slab)[row * 32 + (gc ^ (row & 7))] = *s;
    }
    __syncthreads();
    f32x4 acc = {};
#pragma unroll
    for (int ks = 0; ks < 8; ++ks) {
      bf16x8 a = *(const bf16x8*)&slab[(arow * 32 + ((ks * 4 + lg) ^ (arow & 7))) * 8];
#pragma unroll
      for (int sp = 0; sp < 3; ++sp)
        acc = mfma16(a, bwf[ks][sp], acc);
    }
    float* Pt = P1 + (size_t)t * 1048576 + (size_t)kb * 131072;
#pragma unroll
    for (int r = 0; r < 4; ++r)
      Pt[(bo + 4 * lg + r) * 1024 + nb * 16 + ll] = acc[r];
  }
}

// ---------- fc1 reduce + LIF(0.1), t-loop, state in regs -> z4bf[t][b][n] ----------
__global__ __launch_bounds__(256) void k_fc1b(const float* __restrict__ P1,
    unsigned short* __restrict__ z4bf)
{
  const int site = blockIdx.x * 256 + threadIdx.x;   // 131072 = b*1024+n
  float v = 0.f, ii = 0.f;
  for (int t = 0; t < 16; ++t) {
    const float* p = P1 + (size_t)t * 1048576 + site;
    float a = 0.f;
#pragma unroll
    for (int kb = 0; kb < 8; ++kb) a += p[(size_t)kb * 131072];
    float z = lif1(a, 0.1f, v, ii);
    z4bf[(size_t)t * 131072 + site] = f2bf(z);
  }
}

// ---------- out layer (1024->10) + LI + running max, t-loop, state in regs ----------
__global__ __launch_bounds__(256) void k_out(const unsigned short* __restrict__ z4bf,
    const float* __restrict__ wo, float* __restrict__ out)
{
  const int w = threadIdx.x >> 6, l = threadIdx.x & 63;
  const int b = blockIdx.x * 4 + w;
  float vo[10], io[10], om[10];
#pragma unroll
  for (int o = 0; o < 10; ++o) { vo[o] = 0.f; io[o] = 0.f; om[o] = 0.f; }
  for (int t = 0; t < 16; ++t) {
    float dot[10];
#pragma unroll
    for (int o = 0; o < 10; ++o) dot[o] = 0.f;
    for (int c = 0; c < 16; ++c) {
      const int n = c * 64 + l;
      float z = bf2f(z4bf[(size_t)t * 131072 + b * 1024 + n]);
#pragma unroll
      for (int o = 0; o < 10; ++o) dot[o] = fmaf(z, wo[o * 1024 + n], dot[o]);
    }
#pragma unroll
    for (int o = 0; o < 10; ++o)
#pragma unroll
      for (int d = 32; d > 0; d >>= 1) dot[o] += __shfl_down(dot[o], d);
    if (l == 0) {
#pragma unroll
      for (int o = 0; o < 10; ++o) {
        float vn = fmaf(0.1f, io[o] - vo[o], vo[o]);
        io[o] = fmaf(0.8f, io[o], dot[o]);
        vo[o] = vn;
        om[o] = (t == 0) ? vn : fmaxf(om[o], vn);
      }
    }
  }
  if (l == 0) {
#pragma unroll
    for (int o = 0; o < 10; ++o) out[b * 10 + o] = om[o];
  }
}

extern "C" void kernel_launch(void* const* d_in, const int* in_sizes, int n_in,
                              void* d_out, int out_size, void* d_ws, size_t ws_size,
                              hipStream_t stream)
{
  const float* x   = (const float*)d_in[0];   // (16,128,3,32,32)
  const float* wc1 = (const float*)d_in[1];   // (32,3,3,3)
  const float* wc2 = (const float*)d_in[2];   // (64,32,3,3)
  const float* wc3 = (const float*)d_in[3];   // (128,64,3,3)
  const float* wf1 = (const float*)d_in[4];   // (1024,2048)
  const float* wo  = (const float*)d_in[5];   // (10,1024)
  float* out = (float*)d_out;                 // (128,10)
  char* ws = (char*)d_ws;

  unsigned short* z1bf = (unsigned short*)(ws + 0);          // [16][128,16,16,32]
  unsigned short* z2bf = (unsigned short*)(ws + 33554432);   // [16][128,8,8,64]
  unsigned short* z3t  = (unsigned short*)(ws + 50331648);   // [16][128,2048]
  unsigned short* z4bf = (unsigned short*)(ws + 58720256);   // [16][128,1024]
  float* P1            = (float*)(ws + 62914560);            // [16][8][131072]
  unsigned short* wc2pk = (unsigned short*)(ws + 130023424);
  unsigned short* wc3pk = (unsigned short*)(ws + 130134016);

  k_pack2<<<216, 256, 0, stream>>>(wc2, wc2pk);
  k_pack3<<<1728, 256, 0, stream>>>(wc3, wc3pk);

  k_conv1<<<1024, 256, 0, stream>>>(x, wc1, z1bf);
  k_conv2<<<512, 256, 0, stream>>>(z1bf, wc2pk, z2bf);
  k_conv3<<<1024, 256, 0, stream>>>(z2bf, wc3pk, z3t);
  k_fc1 <<<1024, 256, 0, stream>>>(z3t, wf1, P1);
  k_fc1b<<<512, 256, 0, stream>>>(P1, z4bf);
  k_out <<<32, 256, 0, stream>>>(z4bf, wo, out);
}

// Round 19
// 361.731 us; speedup vs baseline: 1.8421x; 1.0221x over previous
//
#include <hip/hip_runtime.h>

// ConvSNN forward, T=16, B=128. One kernel per LAYER, t-loop inside, LIF state
// in REGISTERS. conv2/conv3/fc1 via MFMA bf16 with TRIPLE-split weights
// (hi+mid+lo ~= fp32 to ~2^-27 rel); activations are pooled spikes, exact bf16.
// B-fragments (t-invariant weights) in REGISTERS.
// THIS ROUND: conv2/conv3 pooling moved fully into registers: column pairs are
// in-thread (r-pairs), row pairs are lane l<->l^32 (__shfl_xor 32). zpl LDS
// buffers deleted -> conv2 DS-ops/wave-t 74->46, conv3 26->18. Outputs exact
// (spike sums are small integers).

typedef __attribute__((ext_vector_type(8))) short bf16x8;
typedef __attribute__((ext_vector_type(4))) float f32x4;

__device__ __forceinline__ unsigned short f2bf(float f) {
  unsigned int u = __float_as_uint(f);
  return (unsigned short)((u + 0x7fffu + ((u >> 16) & 1u)) >> 16);
}
__device__ __forceinline__ float bf2f(unsigned short h) {
  return __uint_as_float(((unsigned int)h) << 16);
}
__device__ __forceinline__ unsigned short split3(float wv, int sp) {
  unsigned short hi = f2bf(wv);
  float r1 = wv - bf2f(hi);
  unsigned short mid = f2bf(r1);
  if (sp == 0) return hi;
  if (sp == 1) return mid;
  return f2bf(r1 - bf2f(mid));
}
__device__ __forceinline__ float lif1(float inp, float vth, float& v, float& i) {
  float vd = fmaf(0.1f, i - v, v);
  float z = (vd > vth) ? 1.0f : 0.0f;
  v = (vd > vth) ? 0.0f : vd;
  i = fmaf(0.8f, i, inp);
  return z;
}
__device__ __forceinline__ f32x4 mfma16(bf16x8 a, bf16x8 b, f32x4 c) {
  return __builtin_amdgcn_mfma_f32_16x16x32_bf16(a, b, c, 0, 0, 0);
}

// ---------- one-time weight split+pack into B-fragment order ----------
// conv2 layout: [ocg 4][sp 3][dydx 9][g 4][ocl 16][j 8]  (ic = 8g+j); 55296
__global__ __launch_bounds__(256) void k_pack2(const float* __restrict__ wc2,
                                               unsigned short* __restrict__ wpk) {
  int idx = blockIdx.x * 256 + threadIdx.x;
  if (idx >= 55296) return;
  int j = idx & 7, ocl = (idx >> 3) & 15, g = (idx >> 7) & 3;
  int r = idx >> 9;                         // 0..107
  int dydx = r % 9; int q = r / 9;          // 0..11
  int sp = q % 3, ocg = q / 3;
  int oc = ocg * 16 + ocl, ic = g * 8 + j;
  wpk[idx] = split3(wc2[(oc * 32 + ic) * 9 + dydx], sp);
}
// conv3 layout: [ocg 8][ics 2][sp 3][dydx 9][g 4][ocl 16][j 8]; 442368
__global__ __launch_bounds__(256) void k_pack3(const float* __restrict__ wc3,
                                               unsigned short* __restrict__ wpk) {
  int idx = blockIdx.x * 256 + threadIdx.x;
  if (idx >= 442368) return;
  int j = idx & 7, ocl = (idx >> 3) & 15, g = (idx >> 7) & 3;
  int r = idx >> 9;
  int dydx = r % 9; int q = r / 9;
  int sp = q % 3; int q2 = q / 3;
  int ics = q2 & 1, ocg = q2 >> 1;
  int oc = ocg * 16 + ocl, ic = ics * 32 + g * 8 + j;
  wpk[idx] = split3(wc3[(oc * 64 + ic) * 9 + dydx], sp);
}

// ---------- conv1 (3->32) fp32, double-buffered LDS, 1 barrier/t ----------
// grid 1024 = b(128) x h(2) x g(4: 8 oc); 256 thr = 128 sites x 2 sub(4 oc each).
__global__ __launch_bounds__(256) void k_conv1(const float* __restrict__ x,
    const float* __restrict__ wc, unsigned short* __restrict__ z1bf)
{
  const int bid = blockIdx.x;
  const int g = bid & 3, h = (bid >> 2) & 1, b = bid >> 3;
  const int tid = threadIdx.x;
  __shared__ float xs[2][3][18][34];           // 2 x 7344 B
  __shared__ __align__(16) float wl[8][28];    // rows padded 27->28
  for (int i = tid; i < 216; i += 256) wl[i / 27][i % 27] = wc[g * 216 + i];
  int ssrc[8];
#pragma unroll
  for (int k2 = 0; k2 < 8; ++k2) {
    int i = tid + k2 * 256;
    int v = -1;
    if (i < 1836) {
      int c = i / 612, rr = i % 612;
      int row = rr / 34, col = rr % 34;
      int gy = h * 16 + row - 1, gx = col - 1;
      if (gy >= 0 && gy < 32 && gx >= 0 && gx < 32) v = c * 1024 + gy * 32 + gx;
    }
    ssrc[k2] = v;
  }
  const int site = tid >> 1, sub = tid & 1;
  const int ph = site >> 4, pw = site & 15;
  const int py = h * 8 + ph;
  float vst[4][4], ist[4][4];
#pragma unroll
  for (int jj = 0; jj < 4; ++jj)
#pragma unroll
    for (int r = 0; r < 4; ++r) { vst[jj][r] = 0.f; ist[jj][r] = 0.f; }

  float vals[8];
  float* xsf0 = &xs[0][0][0][0];
  float* xsf1 = &xs[1][0][0][0];
  {
    const float* xt0 = x + b * 3072;
#pragma unroll
    for (int k2 = 0; k2 < 8; ++k2)
      vals[k2] = (ssrc[k2] >= 0) ? xt0[ssrc[k2]] : 0.f;
#pragma unroll
    for (int k2 = 0; k2 < 8; ++k2) {
      int i = tid + k2 * 256;
      if (i < 1836) xsf0[i] = vals[k2];
    }
    const float* xt1 = x + 393216 + b * 3072;
#pragma unroll
    for (int k2 = 0; k2 < 8; ++k2)
      vals[k2] = (ssrc[k2] >= 0) ? xt1[ssrc[k2]] : 0.f;
  }
  __syncthreads();                             // wl + buf0 staged

  for (int t = 0; t < 16; ++t) {
    float* xw = (t & 1) ? xsf0 : xsf1;         // write target = buf[(t+1)&1]
    const float (*xr)[18][34] = xs[t & 1];     // read buffer
    if (t < 15) {
#pragma unroll
      for (int k2 = 0; k2 < 8; ++k2) {
        int i = tid + k2 * 256;
        if (i < 1836) xw[i] = vals[k2];
      }
    }
    if (t < 14) {
      const float* xt = x + (size_t)(t + 2) * 393216 + b * 3072;
#pragma unroll
      for (int k2 = 0; k2 < 8; ++k2)
        vals[k2] = (ssrc[k2] >= 0) ? xt[ssrc[k2]] : 0.f;
    }
    float p[3][4][4];
#pragma unroll
    for (int c = 0; c < 3; ++c)
#pragma unroll
      for (int r = 0; r < 4; ++r) {
        float2 q0 = *(const float2*)&xr[c][2 * ph + r][2 * pw];
        float2 q1 = *(const float2*)&xr[c][2 * ph + r][2 * pw + 2];
        p[c][r][0] = q0.x; p[c][r][1] = q0.y; p[c][r][2] = q1.x; p[c][r][3] = q1.y;
      }
    unsigned short zout[4];
#pragma unroll
    for (int jj = 0; jj < 4; ++jj) {
      float wreg[28];
      const float4* wrow = (const float4*)&wl[sub * 4 + jj][0];
#pragma unroll
      for (int u = 0; u < 7; ++u) *(float4*)&wreg[u * 4] = wrow[u];
      float s00 = 0, s01 = 0, s10 = 0, s11 = 0;
#pragma unroll
      for (int c = 0; c < 3; ++c)
#pragma unroll
        for (int kh = 0; kh < 3; ++kh)
#pragma unroll
          for (int kw = 0; kw < 3; ++kw) {
            float wvv = wreg[(c * 3 + kh) * 3 + kw];
            s00 = fmaf(p[c][kh][kw],     wvv, s00);
            s01 = fmaf(p[c][kh][kw+1],   wvv, s01);
            s10 = fmaf(p[c][kh+1][kw],   wvv, s10);
            s11 = fmaf(p[c][kh+1][kw+1], wvv, s11);
          }
      float z0 = lif1(s00, 0.25f, vst[jj][0], ist[jj][0]);
      float z1 = lif1(s01, 0.25f, vst[jj][1], ist[jj][1]);
      float z2 = lif1(s10, 0.25f, vst[jj][2], ist[jj][2]);
      float z3 = lif1(s11, 0.25f, vst[jj][3], ist[jj][3]);
      zout[jj] = f2bf(0.25f * (z0 + z1 + z2 + z3));
    }
    *(uint2*)&z1bf[(size_t)t * 1048576 + ((b * 16 + py) * 16 + pw) * 32 + g * 8 + sub * 4]
        = *(uint2*)zout;
    __syncthreads();                           // single barrier per t
  }
}

// ---------- conv2 (32->64) MFMA, B in REGS, dbuf img, in-register pooling ----------
// grid 512 = ocg(4: 16 oc) x b(128); 256 thr = 4 waves.
__global__ __launch_bounds__(256, 2) void k_conv2(const unsigned short* __restrict__ z1bf,
    const unsigned short* __restrict__ wpk, unsigned short* __restrict__ z2bf)
{
  const int ocg = blockIdx.x & 3, b = blockIdx.x >> 2;
  const int tid = threadIdx.x;
  __shared__ __align__(16) unsigned short img[2][18][18][40];   // 2 x 25920 B
  const int w = tid >> 6, l = tid & 63;
  const int lg = l >> 4, ll = l & 15;
  const int ry = ll >> 3, xi = ll & 7;
  bf16x8 bw[3][9];
  {
    const unsigned short* wp = wpk + ocg * 13824;
#pragma unroll
    for (int sp = 0; sp < 3; ++sp)
#pragma unroll
      for (int s9 = 0; s9 < 9; ++s9)
        bw[sp][s9] = *(const bf16x8*)(wp + ((sp * 9 + s9) * 4 + lg) * 128 + ll * 8);
  }
  uint4* imgu4 = (uint4*)&img[0][0][0][0];
  {
    uint4 zz = {0, 0, 0, 0};
    for (int e = tid; e < 1620; e += 256)
      if ((e % 5) == 4) { imgu4[e] = zz; imgu4[1620 + e] = zz; }
  }
  int csrc[6], cdst[6];
#pragma unroll
  for (int k2 = 0; k2 < 6; ++k2) {
    int e = tid + k2 * 256;
    int v = -1, d = 0;
    if (e < 1296) {
      int s = e >> 2, u = e & 3;
      int row = s / 18, col = s % 18;
      int gy = row - 1, gx = col - 1;
      d = s * 5 + u;
      if (gy >= 0 && gy < 16 && gx >= 0 && gx < 16)
        v = ((b * 16 + gy) * 16 + gx) * 32 + u * 8;
    }
    csrc[k2] = v; cdst[k2] = d;
  }
  float vst[2][2][4], ist[2][2][4];
#pragma unroll
  for (int rp = 0; rp < 2; ++rp)
#pragma unroll
    for (int ch = 0; ch < 2; ++ch)
#pragma unroll
      for (int r = 0; r < 4; ++r) { vst[rp][ch][r] = 0.f; ist[rp][ch][r] = 0.f; }

  uint4 vals[6];
  {
#pragma unroll
    for (int k2 = 0; k2 < 6; ++k2) {
      uint4 val = {0, 0, 0, 0};
      if (csrc[k2] >= 0) val = *(const uint4*)(z1bf + csrc[k2]);
      vals[k2] = val;
    }
#pragma unroll
    for (int k2 = 0; k2 < 6; ++k2) {
      int e = tid + k2 * 256;
      if (e < 1296) imgu4[cdst[k2]] = vals[k2];
    }
    const unsigned short* zt1 = z1bf + 1048576;
#pragma unroll
    for (int k2 = 0; k2 < 6; ++k2) {
      uint4 val = {0, 0, 0, 0};
      if (csrc[k2] >= 0) val = *(const uint4*)(zt1 + csrc[k2]);
      vals[k2] = val;
    }
  }
  __syncthreads();                             // buf0 staged

  for (int t = 0; t < 16; ++t) {
    const int cur = t & 1, nxt = cur ^ 1;
    if (t < 15) {
#pragma unroll
      for (int k2 = 0; k2 < 6; ++k2) {
        int e = tid + k2 * 256;
        if (e < 1296) imgu4[nxt * 1620 + cdst[k2]] = vals[k2];
      }
    }
    if (t < 14) {
      const unsigned short* zt = z1bf + (size_t)(t + 2) * 1048576;
#pragma unroll
      for (int k2 = 0; k2 < 6; ++k2) {
        uint4 val = {0, 0, 0, 0};
        if (csrc[k2] >= 0) val = *(const uint4*)(zt + csrc[k2]);
        vals[k2] = val;
      }
    }
    f32x4 acc[2][2] = {};
#pragma unroll
    for (int s9 = 0; s9 < 9; ++s9) {
      const int dy = s9 / 3, dx = s9 % 3;
      bf16x8 a[2][2];
#pragma unroll
      for (int rp = 0; rp < 2; ++rp)
#pragma unroll
        for (int ch = 0; ch < 2; ++ch)
          a[rp][ch] = *(const bf16x8*)&img[cur][4 * w + 2 * rp + ry + dy][ch * 8 + xi + dx][8 * lg];
#pragma unroll
      for (int sp = 0; sp < 3; ++sp)
#pragma unroll
        for (int rp = 0; rp < 2; ++rp)
#pragma unroll
          for (int ch = 0; ch < 2; ++ch)
            acc[rp][ch] = mfma16(a[rp][ch], bw[sp][s9], acc[rp][ch]);
    }
    // LIF (all lanes, per pre-pool pixel) + in-register 2x2 pool:
    // col pairs in-thread (r 0+1, 2+3); row pairs via lane l <-> l^32.
    float ps[2][2][2];
#pragma unroll
    for (int rp = 0; rp < 2; ++rp)
#pragma unroll
      for (int ch = 0; ch < 2; ++ch) {
        float z0 = lif1(acc[rp][ch][0], 0.2f, vst[rp][ch][0], ist[rp][ch][0]);
        float z1 = lif1(acc[rp][ch][1], 0.2f, vst[rp][ch][1], ist[rp][ch][1]);
        float z2 = lif1(acc[rp][ch][2], 0.2f, vst[rp][ch][2], ist[rp][ch][2]);
        float z3 = lif1(acc[rp][ch][3], 0.2f, vst[rp][ch][3], ist[rp][ch][3]);
        ps[rp][ch][0] = z0 + z1;
        ps[rp][ch][1] = z2 + z3;
      }
#pragma unroll
    for (int rp = 0; rp < 2; ++rp)
#pragma unroll
      for (int ch = 0; ch < 2; ++ch)
#pragma unroll
        for (int q = 0; q < 2; ++q)
          ps[rp][ch][q] += __shfl_xor(ps[rp][ch][q], 32);
    if (lg < 2) {
      const int pcb = 2 * (lg & 1);
#pragma unroll
      for (int rp = 0; rp < 2; ++rp)
#pragma unroll
        for (int ch = 0; ch < 2; ++ch)
#pragma unroll
          for (int q = 0; q < 2; ++q)
            z2bf[(size_t)t * 524288 +
                 ((b * 8 + 2 * w + rp) * 8 + ch * 4 + pcb + q) * 64 + ocg * 16 + ll]
                = f2bf(0.25f * ps[rp][ch][q]);
    }
    __syncthreads();                           // single barrier per t
  }
}

// ---------- conv3 (64->128) MFMA full-K, B in REGS, dbuf img, in-register pooling ----------
// grid 1024 = ocg(8: 16 oc) x b(128); 256 thr = 4 waves (row-pairs).
__global__ __launch_bounds__(256, 2) void k_conv3(const unsigned short* __restrict__ z2bf,
    const unsigned short* __restrict__ wpk, unsigned short* __restrict__ z3t)
{
  const int bid = blockIdx.x;
  const int ocg = bid & 7, b = bid >> 3;
  const int tid = threadIdx.x;
  __shared__ __align__(16) unsigned short img[2][10][12][80];   // 2 x 19200 B
  const int w = tid >> 6, l = tid & 63;
  const int lg = l >> 4, ll = l & 15;
  const int ry = ll >> 3, xi = ll & 7;
  bf16x8 bw[2][3][9];
  {
    const unsigned short* wp = wpk + ocg * 27648;
#pragma unroll
    for (int ics = 0; ics < 2; ++ics)
#pragma unroll
      for (int sp = 0; sp < 3; ++sp)
#pragma unroll
        for (int s9 = 0; s9 < 9; ++s9)
          bw[ics][sp][s9] = *(const bf16x8*)(wp + ics * 13824 +
                                             ((sp * 9 + s9) * 4 + lg) * 128 + ll * 8);
  }
  uint4* imgu4 = (uint4*)&img[0][0][0][0];
  // cell = 10 u4 (8 data + 2 pad). pad written once for both buffers.
  {
    uint4 zz = {0, 0, 0, 0};
    for (int e = tid; e < 1200; e += 256) {
      int u = e % 10;
      if (u >= 8) { imgu4[e] = zz; imgu4[1200 + e] = zz; }
    }
  }
  int csrc[4], cdst[4];
#pragma unroll
  for (int k2 = 0; k2 < 4; ++k2) {
    int e = tid + k2 * 256;
    int v = -1, d = 0;
    {
      int s = e >> 3, u = e & 7;          // e < 960: 120 cells x 8 data u4
      int row = s / 12, col = s % 12;
      int gy = row - 1, gx = col - 1;
      d = s * 10 + u;
      if (gy >= 0 && gy < 8 && gx >= 0 && gx < 8)
        v = ((b * 8 + gy) * 8 + gx) * 64 + u * 8;
    }
    csrc[k2] = v; cdst[k2] = d;
  }
  float vst[4], ist[4];
#pragma unroll
  for (int r = 0; r < 4; ++r) { vst[r] = 0.f; ist[r] = 0.f; }

  uint4 vals[4];
  {
#pragma unroll
    for (int k2 = 0; k2 < 4; ++k2) {
      uint4 val = {0, 0, 0, 0};
      if (csrc[k2] >= 0) val = *(const uint4*)(z2bf + csrc[k2]);
      vals[k2] = val;
    }
#pragma unroll
    for (int k2 = 0; k2 < 4; ++k2)
      imgu4[cdst[k2]] = vals[k2];
    const unsigned short* zt1 = z2bf + 524288;
#pragma unroll
    for (int k2 = 0; k2 < 4; ++k2) {
      uint4 val = {0, 0, 0, 0};
      if (csrc[k2] >= 0) val = *(const uint4*)(zt1 + csrc[k2]);
      vals[k2] = val;
    }
  }
  __syncthreads();                             // buf0 staged

  for (int t = 0; t < 16; ++t) {
    const int cur = t & 1, nxt = cur ^ 1;
    if (t < 15) {
#pragma unroll
      for (int k2 = 0; k2 < 4; ++k2)
        imgu4[nxt * 1200 + cdst[k2]] = vals[k2];
    }
    if (t < 14) {
      const unsigned short* zt = z2bf + (size_t)(t + 2) * 524288;
#pragma unroll
      for (int k2 = 0; k2 < 4; ++k2) {
        uint4 val = {0, 0, 0, 0};
        if (csrc[k2] >= 0) val = *(const uint4*)(zt + csrc[k2]);
        vals[k2] = val;
      }
    }
    f32x4 acc = {};
#pragma unroll
    for (int ics = 0; ics < 2; ++ics)
#pragma unroll
      for (int s9 = 0; s9 < 9; ++s9) {
        const int dy = s9 / 3, dx = s9 % 3;
        bf16x8 a = *(const bf16x8*)&img[cur][2 * w + ry + dy][xi + dx][ics * 32 + 8 * lg];
#pragma unroll
        for (int sp = 0; sp < 3; ++sp)
          acc = mfma16(a, bw[ics][sp][s9], acc);
      }
    // LIF (all lanes) + in-register 2x2 pool (cols in-thread, rows via l^32)
    {
      float z0 = lif1(acc[0], 0.1f, vst[0], ist[0]);
      float z1 = lif1(acc[1], 0.1f, vst[1], ist[1]);
      float z2 = lif1(acc[2], 0.1f, vst[2], ist[2]);
      float z3 = lif1(acc[3], 0.1f, vst[3], ist[3]);
      float p0 = z0 + z1, p1 = z2 + z3;
      p0 += __shfl_xor(p0, 32);
      p1 += __shfl_xor(p1, 32);
      if (lg < 2) {
        unsigned int pk = (unsigned int)f2bf(0.25f * p0)
                        | ((unsigned int)f2bf(0.25f * p1) << 16);
        *(unsigned int*)&z3t[(size_t)t * 262144 + b * 2048 + (ocg * 16 + ll) * 16
                             + w * 4 + 2 * (lg & 1)] = pk;
      }
    }
    __syncthreads();                           // single barrier per t
  }
}

// ---------- fc1 (2048->1024) MFMA, K-split 8, B in REGS (24 frags) ----------
// grid 1024 = kb8 x nb64(16 n) x bb2; 256 thr = 4 waves (bt). LDS = 32 KB slab only.
__global__ __launch_bounds__(256) void k_fc1(const unsigned short* __restrict__ z3t,
    const float* __restrict__ wf1, float* __restrict__ P1)
{
  const int bid = blockIdx.x;
  const int kb = bid & 7, nb = (bid >> 3) & 63, bb = bid >> 9;
  const int tid = threadIdx.x;
  __shared__ __align__(16) unsigned short slab[16384];  // wl3 staging first, then A-slab
  for (int i = tid; i < 4096; i += 256) {
    int n = i >> 8, k = i & 255;
    float wv = wf1[(size_t)(nb * 16 + n) * 2048 + kb * 256 + k];
    unsigned short hi = f2bf(wv);
    float r1 = wv - bf2f(hi);
    unsigned short mid = f2bf(r1);
    unsigned short lo = f2bf(r1 - bf2f(mid));
    int off = ((k >> 5) * 4 + ((k >> 3) & 3)) * 128 + n * 8 + (k & 7);
    slab[off] = hi; slab[4096 + off] = mid; slab[8192 + off] = lo;
  }
  __syncthreads();
  const int w = tid >> 6, l = tid & 63;
  const int lg = l >> 4, ll = l & 15;
  bf16x8 bwf[8][3];
#pragma unroll
  for (int ks = 0; ks < 8; ++ks)
#pragma unroll
    for (int sp = 0; sp < 3; ++sp)
      bwf[ks][sp] = *(const bf16x8*)&slab[sp * 4096 + (ks * 4 + lg) * 128 + ll * 8];
  const int arow = w * 16 + ll;
  const int bo = bb * 64 + w * 16;

  for (int t = 0; t < 16; ++t) {
    __syncthreads();                      // prior readers of slab done
    for (int gidx = tid; gidx < 2048; gidx += 256) {
      int row = gidx >> 5, gc = gidx & 31;
      const uint4* s = (const uint4*)(z3t + (size_t)t * 262144 +
                                      ((bb * 64 + row) * 2048 + kb * 256 + gc * 8));
      ((uint4*)slab)[row * 32 + (gc ^ (row & 7))] = *s;
    }
    __syncthreads();
    f32x4 acc = {};
#pragma unroll
    for (int ks = 0; ks < 8; ++ks) {
      bf16x8 a = *(const bf16x8*)&slab[(arow * 32 + ((ks * 4 + lg) ^ (arow & 7))) * 8];
#pragma unroll
      for (int sp = 0; sp < 3; ++sp)
        acc = mfma16(a, bwf[ks][sp], acc);
    }
    float* Pt = P1 + (size_t)t * 1048576 + (size_t)kb * 131072;
#pragma unroll
    for (int r = 0; r < 4; ++r)
      Pt[(bo + 4 * lg + r) * 1024 + nb * 16 + ll] = acc[r];
  }
}

// ---------- fc1 reduce + LIF(0.1), t-loop, state in regs -> z4bf[t][b][n] ----------
__global__ __launch_bounds__(256) void k_fc1b(const float* __restrict__ P1,
    unsigned short* __restrict__ z4bf)
{
  const int site = blockIdx.x * 256 + threadIdx.x;   // 131072 = b*1024+n
  float v = 0.f, ii = 0.f;
  for (int t = 0; t < 16; ++t) {
    const float* p = P1 + (size_t)t * 1048576 + site;
    float a = 0.f;
#pragma unroll
    for (int kb = 0; kb < 8; ++kb) a += p[(size_t)kb * 131072];
    float z = lif1(a, 0.1f, v, ii);
    z4bf[(size_t)t * 131072 + site] = f2bf(z);
  }
}

// ---------- out layer (1024->10) + LI + running max, t-loop, state in regs ----------
__global__ __launch_bounds__(256) void k_out(const unsigned short* __restrict__ z4bf,
    const float* __restrict__ wo, float* __restrict__ out)
{
  const int w = threadIdx.x >> 6, l = threadIdx.x & 63;
  const int b = blockIdx.x * 4 + w;
  float vo[10], io[10], om[10];
#pragma unroll
  for (int o = 0; o < 10; ++o) { vo[o] = 0.f; io[o] = 0.f; om[o] = 0.f; }
  for (int t = 0; t < 16; ++t) {
    float dot[10];
#pragma unroll
    for (int o = 0; o < 10; ++o) dot[o] = 0.f;
    for (int c = 0; c < 16; ++c) {
      const int n = c * 64 + l;
      float z = bf2f(z4bf[(size_t)t * 131072 + b * 1024 + n]);
#pragma unroll
      for (int o = 0; o < 10; ++o) dot[o] = fmaf(z, wo[o * 1024 + n], dot[o]);
    }
#pragma unroll
    for (int o = 0; o < 10; ++o)
#pragma unroll
      for (int d = 32; d > 0; d >>= 1) dot[o] += __shfl_down(dot[o], d);
    if (l == 0) {
#pragma unroll
      for (int o = 0; o < 10; ++o) {
        float vn = fmaf(0.1f, io[o] - vo[o], vo[o]);
        io[o] = fmaf(0.8f, io[o], dot[o]);
        vo[o] = vn;
        om[o] = (t == 0) ? vn : fmaxf(om[o], vn);
      }
    }
  }
  if (l == 0) {
#pragma unroll
    for (int o = 0; o < 10; ++o) out[b * 10 + o] = om[o];
  }
}

extern "C" void kernel_launch(void* const* d_in, const int* in_sizes, int n_in,
                              void* d_out, int out_size, void* d_ws, size_t ws_size,
                              hipStream_t stream)
{
  const float* x   = (const float*)d_in[0];   // (16,128,3,32,32)
  const float* wc1 = (const float*)d_in[1];   // (32,3,3,3)
  const float* wc2 = (const float*)d_in[2];   // (64,32,3,3)
  const float* wc3 = (const float*)d_in[3];   // (128,64,3,3)
  const float* wf1 = (const float*)d_in[4];   // (1024,2048)
  const float* wo  = (const float*)d_in[5];   // (10,1024)
  float* out = (float*)d_out;                 // (128,10)
  char* ws = (char*)d_ws;

  unsigned short* z1bf = (unsigned short*)(ws + 0);          // [16][128,16,16,32]
  unsigned short* z2bf = (unsigned short*)(ws + 33554432);   // [16][128,8,8,64]
  unsigned short* z3t  = (unsigned short*)(ws + 50331648);   // [16][128,2048]
  unsigned short* z4bf = (unsigned short*)(ws + 58720256);   // [16][128,1024]
  float* P1            = (float*)(ws + 62914560);            // [16][8][131072]
  unsigned short* wc2pk = (unsigned short*)(ws + 130023424);
  unsigned short* wc3pk = (unsigned short*)(ws + 130134016);

  k_pack2<<<216, 256, 0, stream>>>(wc2, wc2pk);
  k_pack3<<<1728, 256, 0, stream>>>(wc3, wc3pk);

  k_conv1<<<1024, 256, 0, stream>>>(x, wc1, z1bf);
  k_conv2<<<512, 256, 0, stream>>>(z1bf, wc2pk, z2bf);
  k_conv3<<<1024, 256, 0, stream>>>(z2bf, wc3pk, z3t);
  k_fc1 <<<1024, 256, 0, stream>>>(z3t, wf1, P1);
  k_fc1b<<<512, 256, 0, stream>>>(P1, z4bf);
  k_out <<<32, 256, 0, stream>>>(z4bf, wo, out);
}

// Round 20
// 341.278 us; speedup vs baseline: 1.9525x; 1.0599x over previous
//
#include <hip/hip_runtime.h>

// ConvSNN forward, T=16, B=128. One kernel per LAYER, t-loop inside, LIF state
// in REGISTERS. conv2/conv3/fc1 via MFMA bf16 with TRIPLE-split weights
// (hi+mid+lo ~= fp32 to ~2^-27 rel); activations are pooled spikes, exact bf16.
// THIS ROUND: conv3 switched to mfma_f32_32x32x16 (32x32 tiles): A-reads/img
// halved, staging dup 8x -> 2.4x, pooling fully in-thread (D-layout quads).
// Wave holds 108 B-frags (~432 regs) at __launch_bounds__(256,1).

typedef __attribute__((ext_vector_type(8))) short bf16x8;
typedef __attribute__((ext_vector_type(4))) float f32x4;
typedef __attribute__((ext_vector_type(16))) float f32x16;

__device__ __forceinline__ unsigned short f2bf(float f) {
  unsigned int u = __float_as_uint(f);
  return (unsigned short)((u + 0x7fffu + ((u >> 16) & 1u)) >> 16);
}
__device__ __forceinline__ float bf2f(unsigned short h) {
  return __uint_as_float(((unsigned int)h) << 16);
}
__device__ __forceinline__ unsigned short split3(float wv, int sp) {
  unsigned short hi = f2bf(wv);
  float r1 = wv - bf2f(hi);
  unsigned short mid = f2bf(r1);
  if (sp == 0) return hi;
  if (sp == 1) return mid;
  return f2bf(r1 - bf2f(mid));
}
__device__ __forceinline__ float lif1(float inp, float vth, float& v, float& i) {
  float vd = fmaf(0.1f, i - v, v);
  float z = (vd > vth) ? 1.0f : 0.0f;
  v = (vd > vth) ? 0.0f : vd;
  i = fmaf(0.8f, i, inp);
  return z;
}
__device__ __forceinline__ f32x4 mfma16(bf16x8 a, bf16x8 b, f32x4 c) {
  return __builtin_amdgcn_mfma_f32_16x16x32_bf16(a, b, c, 0, 0, 0);
}
__device__ __forceinline__ f32x16 mfma32(bf16x8 a, bf16x8 b, f32x16 c) {
  return __builtin_amdgcn_mfma_f32_32x32x16_bf16(a, b, c, 0, 0, 0);
}

// ---------- one-time weight split+pack into B-fragment order ----------
// conv2 layout: [ocg 4][sp 3][dydx 9][g 4][ocl 16][j 8]  (ic = 8g+j); 55296
__global__ __launch_bounds__(256) void k_pack2(const float* __restrict__ wc2,
                                               unsigned short* __restrict__ wpk) {
  int idx = blockIdx.x * 256 + threadIdx.x;
  if (idx >= 55296) return;
  int j = idx & 7, ocl = (idx >> 3) & 15, g = (idx >> 7) & 3;
  int r = idx >> 9;                         // 0..107
  int dydx = r % 9; int q = r / 9;          // 0..11
  int sp = q % 3, ocg = q / 3;
  int oc = ocg * 16 + ocl, ic = g * 8 + j;
  wpk[idx] = split3(wc2[(oc * 32 + ic) * 9 + dydx], sp);
}
// conv3 (32x32x16 B-frag order): [ot 4][kc 4][sp 3][s9 9][kg 2][oc 32][j 8]; 221184
// oc_g = ot*32+oc; ic = kc*16 + kg*8 + j.
__global__ __launch_bounds__(256) void k_pack3(const float* __restrict__ wc3,
                                               unsigned short* __restrict__ wpk) {
  int idx = blockIdx.x * 256 + threadIdx.x;
  if (idx >= 221184) return;
  int j = idx & 7, oc = (idx >> 3) & 31, kg = (idx >> 8) & 1;
  int rr = idx >> 9;                        // 0..431
  int s9 = rr % 9; int q = rr / 9;          // 0..47
  int sp = q % 3; int q2 = q / 3;           // 0..15
  int kc = q2 & 3, ot = q2 >> 2;
  int oc_g = ot * 32 + oc, ic = kc * 16 + kg * 8 + j;
  wpk[idx] = split3(wc3[(oc_g * 64 + ic) * 9 + s9], sp);
}

// ---------- conv1 (3->32) fp32, double-buffered LDS, 1 barrier/t ----------
// grid 1024 = b(128) x h(2) x g(4: 8 oc); 256 thr = 128 sites x 2 sub(4 oc each).
__global__ __launch_bounds__(256) void k_conv1(const float* __restrict__ x,
    const float* __restrict__ wc, unsigned short* __restrict__ z1bf)
{
  const int bid = blockIdx.x;
  const int g = bid & 3, h = (bid >> 2) & 1, b = bid >> 3;
  const int tid = threadIdx.x;
  __shared__ float xs[2][3][18][34];           // 2 x 7344 B
  __shared__ __align__(16) float wl[8][28];    // rows padded 27->28
  for (int i = tid; i < 216; i += 256) wl[i / 27][i % 27] = wc[g * 216 + i];
  int ssrc[8];
#pragma unroll
  for (int k2 = 0; k2 < 8; ++k2) {
    int i = tid + k2 * 256;
    int v = -1;
    if (i < 1836) {
      int c = i / 612, rr = i % 612;
      int row = rr / 34, col = rr % 34;
      int gy = h * 16 + row - 1, gx = col - 1;
      if (gy >= 0 && gy < 32 && gx >= 0 && gx < 32) v = c * 1024 + gy * 32 + gx;
    }
    ssrc[k2] = v;
  }
  const int site = tid >> 1, sub = tid & 1;
  const int ph = site >> 4, pw = site & 15;
  const int py = h * 8 + ph;
  float vst[4][4], ist[4][4];
#pragma unroll
  for (int jj = 0; jj < 4; ++jj)
#pragma unroll
    for (int r = 0; r < 4; ++r) { vst[jj][r] = 0.f; ist[jj][r] = 0.f; }

  float vals[8];
  float* xsf0 = &xs[0][0][0][0];
  float* xsf1 = &xs[1][0][0][0];
  {
    const float* xt0 = x + b * 3072;
#pragma unroll
    for (int k2 = 0; k2 < 8; ++k2)
      vals[k2] = (ssrc[k2] >= 0) ? xt0[ssrc[k2]] : 0.f;
#pragma unroll
    for (int k2 = 0; k2 < 8; ++k2) {
      int i = tid + k2 * 256;
      if (i < 1836) xsf0[i] = vals[k2];
    }
    const float* xt1 = x + 393216 + b * 3072;
#pragma unroll
    for (int k2 = 0; k2 < 8; ++k2)
      vals[k2] = (ssrc[k2] >= 0) ? xt1[ssrc[k2]] : 0.f;
  }
  __syncthreads();                             // wl + buf0 staged

  for (int t = 0; t < 16; ++t) {
    float* xw = (t & 1) ? xsf0 : xsf1;         // write target = buf[(t+1)&1]
    const float (*xr)[18][34] = xs[t & 1];     // read buffer
    if (t < 15) {
#pragma unroll
      for (int k2 = 0; k2 < 8; ++k2) {
        int i = tid + k2 * 256;
        if (i < 1836) xw[i] = vals[k2];
      }
    }
    if (t < 14) {
      const float* xt = x + (size_t)(t + 2) * 393216 + b * 3072;
#pragma unroll
      for (int k2 = 0; k2 < 8; ++k2)
        vals[k2] = (ssrc[k2] >= 0) ? xt[ssrc[k2]] : 0.f;
    }
    float p[3][4][4];
#pragma unroll
    for (int c = 0; c < 3; ++c)
#pragma unroll
      for (int r = 0; r < 4; ++r) {
        float2 q0 = *(const float2*)&xr[c][2 * ph + r][2 * pw];
        float2 q1 = *(const float2*)&xr[c][2 * ph + r][2 * pw + 2];
        p[c][r][0] = q0.x; p[c][r][1] = q0.y; p[c][r][2] = q1.x; p[c][r][3] = q1.y;
      }
    unsigned short zout[4];
#pragma unroll
    for (int jj = 0; jj < 4; ++jj) {
      float wreg[28];
      const float4* wrow = (const float4*)&wl[sub * 4 + jj][0];
#pragma unroll
      for (int u = 0; u < 7; ++u) *(float4*)&wreg[u * 4] = wrow[u];
      float s00 = 0, s01 = 0, s10 = 0, s11 = 0;
#pragma unroll
      for (int c = 0; c < 3; ++c)
#pragma unroll
        for (int kh = 0; kh < 3; ++kh)
#pragma unroll
          for (int kw = 0; kw < 3; ++kw) {
            float wvv = wreg[(c * 3 + kh) * 3 + kw];
            s00 = fmaf(p[c][kh][kw],     wvv, s00);
            s01 = fmaf(p[c][kh][kw+1],   wvv, s01);
            s10 = fmaf(p[c][kh+1][kw],   wvv, s10);
            s11 = fmaf(p[c][kh+1][kw+1], wvv, s11);
          }
      float z0 = lif1(s00, 0.25f, vst[jj][0], ist[jj][0]);
      float z1 = lif1(s01, 0.25f, vst[jj][1], ist[jj][1]);
      float z2 = lif1(s10, 0.25f, vst[jj][2], ist[jj][2]);
      float z3 = lif1(s11, 0.25f, vst[jj][3], ist[jj][3]);
      zout[jj] = f2bf(0.25f * (z0 + z1 + z2 + z3));
    }
    *(uint2*)&z1bf[(size_t)t * 1048576 + ((b * 16 + py) * 16 + pw) * 32 + g * 8 + sub * 4]
        = *(uint2*)zout;
    __syncthreads();                           // single barrier per t
  }
}

// ---------- conv2 (32->64) MFMA, B in REGS, dbuf img, in-register pooling ----------
// grid 512 = ocg(4: 16 oc) x b(128); 256 thr = 4 waves.
__global__ __launch_bounds__(256, 2) void k_conv2(const unsigned short* __restrict__ z1bf,
    const unsigned short* __restrict__ wpk, unsigned short* __restrict__ z2bf)
{
  const int ocg = blockIdx.x & 3, b = blockIdx.x >> 2;
  const int tid = threadIdx.x;
  __shared__ __align__(16) unsigned short img[2][18][18][40];   // 2 x 25920 B
  const int w = tid >> 6, l = tid & 63;
  const int lg = l >> 4, ll = l & 15;
  const int ry = ll >> 3, xi = ll & 7;
  bf16x8 bw[3][9];
  {
    const unsigned short* wp = wpk + ocg * 13824;
#pragma unroll
    for (int sp = 0; sp < 3; ++sp)
#pragma unroll
      for (int s9 = 0; s9 < 9; ++s9)
        bw[sp][s9] = *(const bf16x8*)(wp + ((sp * 9 + s9) * 4 + lg) * 128 + ll * 8);
  }
  uint4* imgu4 = (uint4*)&img[0][0][0][0];
  {
    uint4 zz = {0, 0, 0, 0};
    for (int e = tid; e < 1620; e += 256)
      if ((e % 5) == 4) { imgu4[e] = zz; imgu4[1620 + e] = zz; }
  }
  int csrc[6], cdst[6];
#pragma unroll
  for (int k2 = 0; k2 < 6; ++k2) {
    int e = tid + k2 * 256;
    int v = -1, d = 0;
    if (e < 1296) {
      int s = e >> 2, u = e & 3;
      int row = s / 18, col = s % 18;
      int gy = row - 1, gx = col - 1;
      d = s * 5 + u;
      if (gy >= 0 && gy < 16 && gx >= 0 && gx < 16)
        v = ((b * 16 + gy) * 16 + gx) * 32 + u * 8;
    }
    csrc[k2] = v; cdst[k2] = d;
  }
  float vst[2][2][4], ist[2][2][4];
#pragma unroll
  for (int rp = 0; rp < 2; ++rp)
#pragma unroll
    for (int ch = 0; ch < 2; ++ch)
#pragma unroll
      for (int r = 0; r < 4; ++r) { vst[rp][ch][r] = 0.f; ist[rp][ch][r] = 0.f; }

  uint4 vals[6];
  {
#pragma unroll
    for (int k2 = 0; k2 < 6; ++k2) {
      uint4 val = {0, 0, 0, 0};
      if (csrc[k2] >= 0) val = *(const uint4*)(z1bf + csrc[k2]);
      vals[k2] = val;
    }
#pragma unroll
    for (int k2 = 0; k2 < 6; ++k2) {
      int e = tid + k2 * 256;
      if (e < 1296) imgu4[cdst[k2]] = vals[k2];
    }
    const unsigned short* zt1 = z1bf + 1048576;
#pragma unroll
    for (int k2 = 0; k2 < 6; ++k2) {
      uint4 val = {0, 0, 0, 0};
      if (csrc[k2] >= 0) val = *(const uint4*)(zt1 + csrc[k2]);
      vals[k2] = val;
    }
  }
  __syncthreads();                             // buf0 staged

  for (int t = 0; t < 16; ++t) {
    const int cur = t & 1, nxt = cur ^ 1;
    if (t < 15) {
#pragma unroll
      for (int k2 = 0; k2 < 6; ++k2) {
        int e = tid + k2 * 256;
        if (e < 1296) imgu4[nxt * 1620 + cdst[k2]] = vals[k2];
      }
    }
    if (t < 14) {
      const unsigned short* zt = z1bf + (size_t)(t + 2) * 1048576;
#pragma unroll
      for (int k2 = 0; k2 < 6; ++k2) {
        uint4 val = {0, 0, 0, 0};
        if (csrc[k2] >= 0) val = *(const uint4*)(zt + csrc[k2]);
        vals[k2] = val;
      }
    }
    f32x4 acc[2][2] = {};
#pragma unroll
    for (int s9 = 0; s9 < 9; ++s9) {
      const int dy = s9 / 3, dx = s9 % 3;
      bf16x8 a[2][2];
#pragma unroll
      for (int rp = 0; rp < 2; ++rp)
#pragma unroll
        for (int ch = 0; ch < 2; ++ch)
          a[rp][ch] = *(const bf16x8*)&img[cur][4 * w + 2 * rp + ry + dy][ch * 8 + xi + dx][8 * lg];
#pragma unroll
      for (int sp = 0; sp < 3; ++sp)
#pragma unroll
        for (int rp = 0; rp < 2; ++rp)
#pragma unroll
          for (int ch = 0; ch < 2; ++ch)
            acc[rp][ch] = mfma16(a[rp][ch], bw[sp][s9], acc[rp][ch]);
    }
    // LIF (all lanes, per pre-pool pixel) + in-register 2x2 pool:
    // col pairs in-thread (r 0+1, 2+3); row pairs via lane l <-> l^32.
    float ps[2][2][2];
#pragma unroll
    for (int rp = 0; rp < 2; ++rp)
#pragma unroll
      for (int ch = 0; ch < 2; ++ch) {
        float z0 = lif1(acc[rp][ch][0], 0.2f, vst[rp][ch][0], ist[rp][ch][0]);
        float z1 = lif1(acc[rp][ch][1], 0.2f, vst[rp][ch][1], ist[rp][ch][1]);
        float z2 = lif1(acc[rp][ch][2], 0.2f, vst[rp][ch][2], ist[rp][ch][2]);
        float z3 = lif1(acc[rp][ch][3], 0.2f, vst[rp][ch][3], ist[rp][ch][3]);
        ps[rp][ch][0] = z0 + z1;
        ps[rp][ch][1] = z2 + z3;
      }
#pragma unroll
    for (int rp = 0; rp < 2; ++rp)
#pragma unroll
      for (int ch = 0; ch < 2; ++ch)
#pragma unroll
        for (int q = 0; q < 2; ++q)
          ps[rp][ch][q] += __shfl_xor(ps[rp][ch][q], 32);
    if (lg < 2) {
      const int pcb = 2 * (lg & 1);
#pragma unroll
      for (int rp = 0; rp < 2; ++rp)
#pragma unroll
        for (int ch = 0; ch < 2; ++ch)
#pragma unroll
          for (int q = 0; q < 2; ++q)
            z2bf[(size_t)t * 524288 +
                 ((b * 8 + 2 * w + rp) * 8 + ch * 4 + pcb + q) * 64 + ocg * 16 + ll]
                = f2bf(0.25f * ps[rp][ch][q]);
    }
    __syncthreads();                           // single barrier per t
  }
}

// ---------- conv3 (64->128) via mfma_32x32x16, B in REGS (108 frags) ----------
// grid 256 = h(2) x b(128); 256 thr = 4 waves (oc-tile of 32).
// Half-image (4 out rows); pooling quads fully in-thread (D-layout).
__global__ __launch_bounds__(256, 1) void k_conv3(const unsigned short* __restrict__ z2bf,
    const unsigned short* __restrict__ wpk, unsigned short* __restrict__ z3t)
{
  const int h = blockIdx.x & 1, b = blockIdx.x >> 1;
  const int tid = threadIdx.x;
  __shared__ __align__(16) unsigned short img[6][10][80];  // rows 4h-1..4h+4, cols -1..8
  const int w = tid >> 6, l = tid & 63;
  const int kg = l >> 5, lo = l & 31;       // A: px = lo; B: oc = lo
  const int yy = lo >> 3, xx = lo & 7;
  // B fragments in registers, loaded once: [kc 4][sp 3][s9 9]
  bf16x8 bw[4][3][9];
#pragma unroll
  for (int kc = 0; kc < 4; ++kc)
#pragma unroll
    for (int sp = 0; sp < 3; ++sp)
#pragma unroll
      for (int s9 = 0; s9 < 9; ++s9)
        bw[kc][sp][s9] = *(const bf16x8*)(wpk +
            (((((w * 4 + kc) * 3 + sp) * 9 + s9) * 2 + kg) << 8) + lo * 8);
  uint4* imgu4 = (uint4*)&img[0][0][0];
  {
    uint4 zz = {0, 0, 0, 0};
    for (int e = tid; e < 120; e += 256) {   // 60 cells x 2 pad u4
      int s = e >> 1, u = 8 + (e & 1);
      imgu4[s * 10 + u] = zz;
    }
  }
  int csrc[2], cdst[2];
#pragma unroll
  for (int k2 = 0; k2 < 2; ++k2) {
    int e = tid + k2 * 256;
    int v = -1, d = 0;
    if (e < 480) {                           // 60 cells x 8 data u4
      int s = e >> 3, u = e & 7;
      int row = s / 10, col = s % 10;
      int gy = 4 * h + row - 1, gx = col - 1;
      d = s * 10 + u;
      if (gy >= 0 && gy < 8 && gx >= 0 && gx < 8)
        v = ((b * 8 + gy) * 8 + gx) * 64 + u * 8;
    }
    csrc[k2] = v; cdst[k2] = d;
  }
  float vst[16], ist[16];
#pragma unroll
  for (int r = 0; r < 16; ++r) { vst[r] = 0.f; ist[r] = 0.f; }

  for (int t = 0; t < 16; ++t) {
    __syncthreads();                         // prior-t img readers done
    {
      const unsigned short* zt = z2bf + (size_t)t * 524288;
#pragma unroll
      for (int k2 = 0; k2 < 2; ++k2) {
        int e = tid + k2 * 256;
        if (e < 480) {
          uint4 val = {0, 0, 0, 0};
          if (csrc[k2] >= 0) val = *(const uint4*)(zt + csrc[k2]);
          imgu4[cdst[k2]] = val;
        }
      }
    }
    __syncthreads();
    f32x16 acc = {};
#pragma unroll
    for (int s9 = 0; s9 < 9; ++s9) {
      const int dy = s9 / 3, dx = s9 % 3;
      const unsigned short* ap = &img[yy + dy][xx + dx][kg * 8];
#pragma unroll
      for (int kc = 0; kc < 4; ++kc) {
        bf16x8 a = *(const bf16x8*)(ap + kc * 16);
#pragma unroll
        for (int sp = 0; sp < 3; ++sp)
          acc = mfma32(a, bw[kc][sp][s9], acc);
      }
    }
    // LIF on 16 pre-pool px (row = (r&3)+8*(r>>2)+4*kg applies to px mapping),
    // then 2x2 pool: quads {0,1,4,5},{2,3,6,7},{8,9,12,13},{10,11,14,15} in-thread.
    float z[16];
#pragma unroll
    for (int r = 0; r < 16; ++r)
      z[r] = lif1(acc[r], 0.1f, vst[r], ist[r]);
    float p00 = z[0] + z[1] + z[4] + z[5];
    float p01 = z[2] + z[3] + z[6] + z[7];
    float p10 = z[8] + z[9] + z[12] + z[13];
    float p11 = z[10] + z[11] + z[14] + z[15];
    unsigned short* zo = z3t + (size_t)t * 262144 + b * 2048 + (w * 32 + lo) * 16;
    unsigned int pk0 = (unsigned int)f2bf(0.25f * p00) | ((unsigned int)f2bf(0.25f * p01) << 16);
    unsigned int pk1 = (unsigned int)f2bf(0.25f * p10) | ((unsigned int)f2bf(0.25f * p11) << 16);
    *(unsigned int*)&zo[(h * 2 + 0) * 4 + 2 * kg] = pk0;
    *(unsigned int*)&zo[(h * 2 + 1) * 4 + 2 * kg] = pk1;
  }
}

// ---------- fc1 (2048->1024) MFMA, K-split 8, B in REGS (24 frags) ----------
// grid 1024 = kb8 x nb64(16 n) x bb2; 256 thr = 4 waves (bt). LDS = 32 KB slab only.
__global__ __launch_bounds__(256) void k_fc1(const unsigned short* __restrict__ z3t,
    const float* __restrict__ wf1, float* __restrict__ P1)
{
  const int bid = blockIdx.x;
  const int kb = bid & 7, nb = (bid >> 3) & 63, bb = bid >> 9;
  const int tid = threadIdx.x;
  __shared__ __align__(16) unsigned short slab[16384];  // wl3 staging first, then A-slab
  for (int i = tid; i < 4096; i += 256) {
    int n = i >> 8, k = i & 255;
    float wv = wf1[(size_t)(nb * 16 + n) * 2048 + kb * 256 + k];
    unsigned short hi = f2bf(wv);
    float r1 = wv - bf2f(hi);
    unsigned short mid = f2bf(r1);
    unsigned short lo = f2bf(r1 - bf2f(mid));
    int off = ((k >> 5) * 4 + ((k >> 3) & 3)) * 128 + n * 8 + (k & 7);
    slab[off] = hi; slab[4096 + off] = mid; slab[8192 + off] = lo;
  }
  __syncthreads();
  const int w = tid >> 6, l = tid & 63;
  const int lg = l >> 4, ll = l & 15;
  bf16x8 bwf[8][3];
#pragma unroll
  for (int ks = 0; ks < 8; ++ks)
#pragma unroll
    for (int sp = 0; sp < 3; ++sp)
      bwf[ks][sp] = *(const bf16x8*)&slab[sp * 4096 + (ks * 4 + lg) * 128 + ll * 8];
  const int arow = w * 16 + ll;
  const int bo = bb * 64 + w * 16;

  for (int t = 0; t < 16; ++t) {
    __syncthreads();                      // prior readers of slab done
    for (int gidx = tid; gidx < 2048; gidx += 256) {
      int row = gidx >> 5, gc = gidx & 31;
      const uint4* s = (const uint4*)(z3t + (size_t)t * 262144 +
                                      ((bb * 64 + row) * 2048 + kb * 256 + gc * 8));
      ((uint4*)slab)[row * 32 + (gc ^ (row & 7))] = *s;
    }
    __syncthreads();
    f32x4 acc = {};
#pragma unroll
    for (int ks = 0; ks < 8; ++ks) {
      bf16x8 a = *(const bf16x8*)&slab[(arow * 32 + ((ks * 4 + lg) ^ (arow & 7))) * 8];
#pragma unroll
      for (int sp = 0; sp < 3; ++sp)
        acc = mfma16(a, bwf[ks][sp], acc);
    }
    float* Pt = P1 + (size_t)t * 1048576 + (size_t)kb * 131072;
#pragma unroll
    for (int r = 0; r < 4; ++r)
      Pt[(bo + 4 * lg + r) * 1024 + nb * 16 + ll] = acc[r];
  }
}

// ---------- fc1 reduce + LIF(0.1), t-loop, state in regs -> z4bf[t][b][n] ----------
__global__ __launch_bounds__(256) void k_fc1b(const float* __restrict__ P1,
    unsigned short* __restrict__ z4bf)
{
  const int site = blockIdx.x * 256 + threadIdx.x;   // 131072 = b*1024+n
  float v = 0.f, ii = 0.f;
  for (int t = 0; t < 16; ++t) {
    const float* p = P1 + (size_t)t * 1048576 + site;
    float a = 0.f;
#pragma unroll
    for (int kb = 0; kb < 8; ++kb) a += p[(size_t)kb * 131072];
    float z = lif1(a, 0.1f, v, ii);
    z4bf[(size_t)t * 131072 + site] = f2bf(z);
  }
}

// ---------- out layer (1024->10) + LI + running max, t-loop, state in regs ----------
__global__ __launch_bounds__(256) void k_out(const unsigned short* __restrict__ z4bf,
    const float* __restrict__ wo, float* __restrict__ out)
{
  const int w = threadIdx.x >> 6, l = threadIdx.x & 63;
  const int b = blockIdx.x * 4 + w;
  float vo[10], io[10], om[10];
#pragma unroll
  for (int o = 0; o < 10; ++o) { vo[o] = 0.f; io[o] = 0.f; om[o] = 0.f; }
  for (int t = 0; t < 16; ++t) {
    float dot[10];
#pragma unroll
    for (int o = 0; o < 10; ++o) dot[o] = 0.f;
    for (int c = 0; c < 16; ++c) {
      const int n = c * 64 + l;
      float z = bf2f(z4bf[(size_t)t * 131072 + b * 1024 + n]);
#pragma unroll
      for (int o = 0; o < 10; ++o) dot[o] = fmaf(z, wo[o * 1024 + n], dot[o]);
    }
#pragma unroll
    for (int o = 0; o < 10; ++o)
#pragma unroll
      for (int d = 32; d > 0; d >>= 1) dot[o] += __shfl_down(dot[o], d);
    if (l == 0) {
#pragma unroll
      for (int o = 0; o < 10; ++o) {
        float vn = fmaf(0.1f, io[o] - vo[o], vo[o]);
        io[o] = fmaf(0.8f, io[o], dot[o]);
        vo[o] = vn;
        om[o] = (t == 0) ? vn : fmaxf(om[o], vn);
      }
    }
  }
  if (l == 0) {
#pragma unroll
    for (int o = 0; o < 10; ++o) out[b * 10 + o] = om[o];
  }
}

extern "C" void kernel_launch(void* const* d_in, const int* in_sizes, int n_in,
                              void* d_out, int out_size, void* d_ws, size_t ws_size,
                              hipStream_t stream)
{
  const float* x   = (const float*)d_in[0];   // (16,128,3,32,32)
  const float* wc1 = (const float*)d_in[1];   // (32,3,3,3)
  const float* wc2 = (const float*)d_in[2];   // (64,32,3,3)
  const float* wc3 = (const float*)d_in[3];   // (128,64,3,3)
  const float* wf1 = (const float*)d_in[4];   // (1024,2048)
  const float* wo  = (const float*)d_in[5];   // (10,1024)
  float* out = (float*)d_out;                 // (128,10)
  char* ws = (char*)d_ws;

  unsigned short* z1bf = (unsigned short*)(ws + 0);          // [16][128,16,16,32]
  unsigned short* z2bf = (unsigned short*)(ws + 33554432);   // [16][128,8,8,64]
  unsigned short* z3t  = (unsigned short*)(ws + 50331648);   // [16][128,2048]
  unsigned short* z4bf = (unsigned short*)(ws + 58720256);   // [16][128,1024]
  float* P1            = (float*)(ws + 62914560);            // [16][8][131072]
  unsigned short* wc2pk = (unsigned short*)(ws + 130023424);
  unsigned short* wc3pk = (unsigned short*)(ws + 130134016); // 221184 sh

  k_pack2<<<216, 256, 0, stream>>>(wc2, wc2pk);
  k_pack3<<<864, 256, 0, stream>>>(wc3, wc3pk);

  k_conv1<<<1024, 256, 0, stream>>>(x, wc1, z1bf);
  k_conv2<<<512, 256, 0, stream>>>(z1bf, wc2pk, z2bf);
  k_conv3<<<256, 256, 0, stream>>>(z2bf, wc3pk, z3t);
  k_fc1 <<<1024, 256, 0, stream>>>(z3t, wf1, P1);
  k_fc1b<<<512, 256, 0, stream>>>(P1, z4bf);
  k_out <<<32, 256, 0, stream>>>(z4bf, wo, out);
}

// Round 21
// 273.220 us; speedup vs baseline: 2.4389x; 1.2491x over previous
//
#include <hip/hip_runtime.h>

// ConvSNN forward, T=16, B=128. One kernel per LAYER, t-loop inside, LIF state
// in REGISTERS. conv2/conv3/fc1 via MFMA bf16 with TRIPLE-split weights
// (hi+mid+lo ~= fp32 to ~2^-27 rel); activations are pooled spikes, exact bf16.
// conv3 via mfma_f32_32x32x16 (B-frags in regs, launch_bounds(256,1)).
// THIS ROUND: k_out (79us, 1.3% occupancy: 128 serial waves) split into
// k_dot (parallel over (t,b): 2048 waves, shfl-reduced 1024-dots -> D[t][b][10])
// + k_li (1280-site 16-step LI recurrence + running max, ~3us).

typedef __attribute__((ext_vector_type(8))) short bf16x8;
typedef __attribute__((ext_vector_type(4))) float f32x4;
typedef __attribute__((ext_vector_type(16))) float f32x16;

__device__ __forceinline__ unsigned short f2bf(float f) {
  unsigned int u = __float_as_uint(f);
  return (unsigned short)((u + 0x7fffu + ((u >> 16) & 1u)) >> 16);
}
__device__ __forceinline__ float bf2f(unsigned short h) {
  return __uint_as_float(((unsigned int)h) << 16);
}
__device__ __forceinline__ unsigned short split3(float wv, int sp) {
  unsigned short hi = f2bf(wv);
  float r1 = wv - bf2f(hi);
  unsigned short mid = f2bf(r1);
  if (sp == 0) return hi;
  if (sp == 1) return mid;
  return f2bf(r1 - bf2f(mid));
}
__device__ __forceinline__ float lif1(float inp, float vth, float& v, float& i) {
  float vd = fmaf(0.1f, i - v, v);
  float z = (vd > vth) ? 1.0f : 0.0f;
  v = (vd > vth) ? 0.0f : vd;
  i = fmaf(0.8f, i, inp);
  return z;
}
__device__ __forceinline__ f32x4 mfma16(bf16x8 a, bf16x8 b, f32x4 c) {
  return __builtin_amdgcn_mfma_f32_16x16x32_bf16(a, b, c, 0, 0, 0);
}
__device__ __forceinline__ f32x16 mfma32(bf16x8 a, bf16x8 b, f32x16 c) {
  return __builtin_amdgcn_mfma_f32_32x32x16_bf16(a, b, c, 0, 0, 0);
}

// ---------- one-time weight split+pack into B-fragment order ----------
// conv2 layout: [ocg 4][sp 3][dydx 9][g 4][ocl 16][j 8]  (ic = 8g+j); 55296
__global__ __launch_bounds__(256) void k_pack2(const float* __restrict__ wc2,
                                               unsigned short* __restrict__ wpk) {
  int idx = blockIdx.x * 256 + threadIdx.x;
  if (idx >= 55296) return;
  int j = idx & 7, ocl = (idx >> 3) & 15, g = (idx >> 7) & 3;
  int r = idx >> 9;                         // 0..107
  int dydx = r % 9; int q = r / 9;          // 0..11
  int sp = q % 3, ocg = q / 3;
  int oc = ocg * 16 + ocl, ic = g * 8 + j;
  wpk[idx] = split3(wc2[(oc * 32 + ic) * 9 + dydx], sp);
}
// conv3 (32x32x16 B-frag order): [ot 4][kc 4][sp 3][s9 9][kg 2][oc 32][j 8]; 221184
__global__ __launch_bounds__(256) void k_pack3(const float* __restrict__ wc3,
                                               unsigned short* __restrict__ wpk) {
  int idx = blockIdx.x * 256 + threadIdx.x;
  if (idx >= 221184) return;
  int j = idx & 7, oc = (idx >> 3) & 31, kg = (idx >> 8) & 1;
  int rr = idx >> 9;                        // 0..431
  int s9 = rr % 9; int q = rr / 9;          // 0..47
  int sp = q % 3; int q2 = q / 3;           // 0..15
  int kc = q2 & 3, ot = q2 >> 2;
  int oc_g = ot * 32 + oc, ic = kc * 16 + kg * 8 + j;
  wpk[idx] = split3(wc3[(oc_g * 64 + ic) * 9 + s9], sp);
}

// ---------- conv1 (3->32) fp32, double-buffered LDS, 1 barrier/t ----------
// grid 1024 = b(128) x h(2) x g(4: 8 oc); 256 thr = 128 sites x 2 sub(4 oc each).
__global__ __launch_bounds__(256) void k_conv1(const float* __restrict__ x,
    const float* __restrict__ wc, unsigned short* __restrict__ z1bf)
{
  const int bid = blockIdx.x;
  const int g = bid & 3, h = (bid >> 2) & 1, b = bid >> 3;
  const int tid = threadIdx.x;
  __shared__ float xs[2][3][18][34];           // 2 x 7344 B
  __shared__ __align__(16) float wl[8][28];    // rows padded 27->28
  for (int i = tid; i < 216; i += 256) wl[i / 27][i % 27] = wc[g * 216 + i];
  int ssrc[8];
#pragma unroll
  for (int k2 = 0; k2 < 8; ++k2) {
    int i = tid + k2 * 256;
    int v = -1;
    if (i < 1836) {
      int c = i / 612, rr = i % 612;
      int row = rr / 34, col = rr % 34;
      int gy = h * 16 + row - 1, gx = col - 1;
      if (gy >= 0 && gy < 32 && gx >= 0 && gx < 32) v = c * 1024 + gy * 32 + gx;
    }
    ssrc[k2] = v;
  }
  const int site = tid >> 1, sub = tid & 1;
  const int ph = site >> 4, pw = site & 15;
  const int py = h * 8 + ph;
  float vst[4][4], ist[4][4];
#pragma unroll
  for (int jj = 0; jj < 4; ++jj)
#pragma unroll
    for (int r = 0; r < 4; ++r) { vst[jj][r] = 0.f; ist[jj][r] = 0.f; }

  float vals[8];
  float* xsf0 = &xs[0][0][0][0];
  float* xsf1 = &xs[1][0][0][0];
  {
    const float* xt0 = x + b * 3072;
#pragma unroll
    for (int k2 = 0; k2 < 8; ++k2)
      vals[k2] = (ssrc[k2] >= 0) ? xt0[ssrc[k2]] : 0.f;
#pragma unroll
    for (int k2 = 0; k2 < 8; ++k2) {
      int i = tid + k2 * 256;
      if (i < 1836) xsf0[i] = vals[k2];
    }
    const float* xt1 = x + 393216 + b * 3072;
#pragma unroll
    for (int k2 = 0; k2 < 8; ++k2)
      vals[k2] = (ssrc[k2] >= 0) ? xt1[ssrc[k2]] : 0.f;
  }
  __syncthreads();                             // wl + buf0 staged

  for (int t = 0; t < 16; ++t) {
    float* xw = (t & 1) ? xsf0 : xsf1;         // write target = buf[(t+1)&1]
    const float (*xr)[18][34] = xs[t & 1];     // read buffer
    if (t < 15) {
#pragma unroll
      for (int k2 = 0; k2 < 8; ++k2) {
        int i = tid + k2 * 256;
        if (i < 1836) xw[i] = vals[k2];
      }
    }
    if (t < 14) {
      const float* xt = x + (size_t)(t + 2) * 393216 + b * 3072;
#pragma unroll
      for (int k2 = 0; k2 < 8; ++k2)
        vals[k2] = (ssrc[k2] >= 0) ? xt[ssrc[k2]] : 0.f;
    }
    float p[3][4][4];
#pragma unroll
    for (int c = 0; c < 3; ++c)
#pragma unroll
      for (int r = 0; r < 4; ++r) {
        float2 q0 = *(const float2*)&xr[c][2 * ph + r][2 * pw];
        float2 q1 = *(const float2*)&xr[c][2 * ph + r][2 * pw + 2];
        p[c][r][0] = q0.x; p[c][r][1] = q0.y; p[c][r][2] = q1.x; p[c][r][3] = q1.y;
      }
    unsigned short zout[4];
#pragma unroll
    for (int jj = 0; jj < 4; ++jj) {
      float wreg[28];
      const float4* wrow = (const float4*)&wl[sub * 4 + jj][0];
#pragma unroll
      for (int u = 0; u < 7; ++u) *(float4*)&wreg[u * 4] = wrow[u];
      float s00 = 0, s01 = 0, s10 = 0, s11 = 0;
#pragma unroll
      for (int c = 0; c < 3; ++c)
#pragma unroll
        for (int kh = 0; kh < 3; ++kh)
#pragma unroll
          for (int kw = 0; kw < 3; ++kw) {
            float wvv = wreg[(c * 3 + kh) * 3 + kw];
            s00 = fmaf(p[c][kh][kw],     wvv, s00);
            s01 = fmaf(p[c][kh][kw+1],   wvv, s01);
            s10 = fmaf(p[c][kh+1][kw],   wvv, s10);
            s11 = fmaf(p[c][kh+1][kw+1], wvv, s11);
          }
      float z0 = lif1(s00, 0.25f, vst[jj][0], ist[jj][0]);
      float z1 = lif1(s01, 0.25f, vst[jj][1], ist[jj][1]);
      float z2 = lif1(s10, 0.25f, vst[jj][2], ist[jj][2]);
      float z3 = lif1(s11, 0.25f, vst[jj][3], ist[jj][3]);
      zout[jj] = f2bf(0.25f * (z0 + z1 + z2 + z3));
    }
    *(uint2*)&z1bf[(size_t)t * 1048576 + ((b * 16 + py) * 16 + pw) * 32 + g * 8 + sub * 4]
        = *(uint2*)zout;
    __syncthreads();                           // single barrier per t
  }
}

// ---------- conv2 (32->64) MFMA, B in REGS, dbuf img, in-register pooling ----------
// grid 512 = ocg(4: 16 oc) x b(128); 256 thr = 4 waves.
__global__ __launch_bounds__(256, 2) void k_conv2(const unsigned short* __restrict__ z1bf,
    const unsigned short* __restrict__ wpk, unsigned short* __restrict__ z2bf)
{
  const int ocg = blockIdx.x & 3, b = blockIdx.x >> 2;
  const int tid = threadIdx.x;
  __shared__ __align__(16) unsigned short img[2][18][18][40];   // 2 x 25920 B
  const int w = tid >> 6, l = tid & 63;
  const int lg = l >> 4, ll = l & 15;
  const int ry = ll >> 3, xi = ll & 7;
  bf16x8 bw[3][9];
  {
    const unsigned short* wp = wpk + ocg * 13824;
#pragma unroll
    for (int sp = 0; sp < 3; ++sp)
#pragma unroll
      for (int s9 = 0; s9 < 9; ++s9)
        bw[sp][s9] = *(const bf16x8*)(wp + ((sp * 9 + s9) * 4 + lg) * 128 + ll * 8);
  }
  uint4* imgu4 = (uint4*)&img[0][0][0][0];
  {
    uint4 zz = {0, 0, 0, 0};
    for (int e = tid; e < 1620; e += 256)
      if ((e % 5) == 4) { imgu4[e] = zz; imgu4[1620 + e] = zz; }
  }
  int csrc[6], cdst[6];
#pragma unroll
  for (int k2 = 0; k2 < 6; ++k2) {
    int e = tid + k2 * 256;
    int v = -1, d = 0;
    if (e < 1296) {
      int s = e >> 2, u = e & 3;
      int row = s / 18, col = s % 18;
      int gy = row - 1, gx = col - 1;
      d = s * 5 + u;
      if (gy >= 0 && gy < 16 && gx >= 0 && gx < 16)
        v = ((b * 16 + gy) * 16 + gx) * 32 + u * 8;
    }
    csrc[k2] = v; cdst[k2] = d;
  }
  float vst[2][2][4], ist[2][2][4];
#pragma unroll
  for (int rp = 0; rp < 2; ++rp)
#pragma unroll
    for (int ch = 0; ch < 2; ++ch)
#pragma unroll
      for (int r = 0; r < 4; ++r) { vst[rp][ch][r] = 0.f; ist[rp][ch][r] = 0.f; }

  uint4 vals[6];
  {
#pragma unroll
    for (int k2 = 0; k2 < 6; ++k2) {
      uint4 val = {0, 0, 0, 0};
      if (csrc[k2] >= 0) val = *(const uint4*)(z1bf + csrc[k2]);
      vals[k2] = val;
    }
#pragma unroll
    for (int k2 = 0; k2 < 6; ++k2) {
      int e = tid + k2 * 256;
      if (e < 1296) imgu4[cdst[k2]] = vals[k2];
    }
    const unsigned short* zt1 = z1bf + 1048576;
#pragma unroll
    for (int k2 = 0; k2 < 6; ++k2) {
      uint4 val = {0, 0, 0, 0};
      if (csrc[k2] >= 0) val = *(const uint4*)(zt1 + csrc[k2]);
      vals[k2] = val;
    }
  }
  __syncthreads();                             // buf0 staged

  for (int t = 0; t < 16; ++t) {
    const int cur = t & 1, nxt = cur ^ 1;
    if (t < 15) {
#pragma unroll
      for (int k2 = 0; k2 < 6; ++k2) {
        int e = tid + k2 * 256;
        if (e < 1296) imgu4[nxt * 1620 + cdst[k2]] = vals[k2];
      }
    }
    if (t < 14) {
      const unsigned short* zt = z1bf + (size_t)(t + 2) * 1048576;
#pragma unroll
      for (int k2 = 0; k2 < 6; ++k2) {
        uint4 val = {0, 0, 0, 0};
        if (csrc[k2] >= 0) val = *(const uint4*)(zt + csrc[k2]);
        vals[k2] = val;
      }
    }
    f32x4 acc[2][2] = {};
#pragma unroll
    for (int s9 = 0; s9 < 9; ++s9) {
      const int dy = s9 / 3, dx = s9 % 3;
      bf16x8 a[2][2];
#pragma unroll
      for (int rp = 0; rp < 2; ++rp)
#pragma unroll
        for (int ch = 0; ch < 2; ++ch)
          a[rp][ch] = *(const bf16x8*)&img[cur][4 * w + 2 * rp + ry + dy][ch * 8 + xi + dx][8 * lg];
#pragma unroll
      for (int sp = 0; sp < 3; ++sp)
#pragma unroll
        for (int rp = 0; rp < 2; ++rp)
#pragma unroll
          for (int ch = 0; ch < 2; ++ch)
            acc[rp][ch] = mfma16(a[rp][ch], bw[sp][s9], acc[rp][ch]);
    }
    float ps[2][2][2];
#pragma unroll
    for (int rp = 0; rp < 2; ++rp)
#pragma unroll
      for (int ch = 0; ch < 2; ++ch) {
        float z0 = lif1(acc[rp][ch][0], 0.2f, vst[rp][ch][0], ist[rp][ch][0]);
        float z1 = lif1(acc[rp][ch][1], 0.2f, vst[rp][ch][1], ist[rp][ch][1]);
        float z2 = lif1(acc[rp][ch][2], 0.2f, vst[rp][ch][2], ist[rp][ch][2]);
        float z3 = lif1(acc[rp][ch][3], 0.2f, vst[rp][ch][3], ist[rp][ch][3]);
        ps[rp][ch][0] = z0 + z1;
        ps[rp][ch][1] = z2 + z3;
      }
#pragma unroll
    for (int rp = 0; rp < 2; ++rp)
#pragma unroll
      for (int ch = 0; ch < 2; ++ch)
#pragma unroll
        for (int q = 0; q < 2; ++q)
          ps[rp][ch][q] += __shfl_xor(ps[rp][ch][q], 32);
    if (lg < 2) {
      const int pcb = 2 * (lg & 1);
#pragma unroll
      for (int rp = 0; rp < 2; ++rp)
#pragma unroll
        for (int ch = 0; ch < 2; ++ch)
#pragma unroll
          for (int q = 0; q < 2; ++q)
            z2bf[(size_t)t * 524288 +
                 ((b * 8 + 2 * w + rp) * 8 + ch * 4 + pcb + q) * 64 + ocg * 16 + ll]
                = f2bf(0.25f * ps[rp][ch][q]);
    }
    __syncthreads();                           // single barrier per t
  }
}

// ---------- conv3 (64->128) via mfma_32x32x16, B in REGS (108 frags) ----------
// grid 256 = h(2) x b(128); 256 thr = 4 waves (oc-tile of 32).
__global__ __launch_bounds__(256, 1) void k_conv3(const unsigned short* __restrict__ z2bf,
    const unsigned short* __restrict__ wpk, unsigned short* __restrict__ z3t)
{
  const int h = blockIdx.x & 1, b = blockIdx.x >> 1;
  const int tid = threadIdx.x;
  __shared__ __align__(16) unsigned short img[6][10][80];  // rows 4h-1..4h+4, cols -1..8
  const int w = tid >> 6, l = tid & 63;
  const int kg = l >> 5, lo = l & 31;       // A: px = lo; B: oc = lo
  const int yy = lo >> 3, xx = lo & 7;
  bf16x8 bw[4][3][9];
#pragma unroll
  for (int kc = 0; kc < 4; ++kc)
#pragma unroll
    for (int sp = 0; sp < 3; ++sp)
#pragma unroll
      for (int s9 = 0; s9 < 9; ++s9)
        bw[kc][sp][s9] = *(const bf16x8*)(wpk +
            (((((w * 4 + kc) * 3 + sp) * 9 + s9) * 2 + kg) << 8) + lo * 8);
  uint4* imgu4 = (uint4*)&img[0][0][0];
  {
    uint4 zz = {0, 0, 0, 0};
    for (int e = tid; e < 120; e += 256) {   // 60 cells x 2 pad u4
      int s = e >> 1, u = 8 + (e & 1);
      imgu4[s * 10 + u] = zz;
    }
  }
  int csrc[2], cdst[2];
#pragma unroll
  for (int k2 = 0; k2 < 2; ++k2) {
    int e = tid + k2 * 256;
    int v = -1, d = 0;
    if (e < 480) {                           // 60 cells x 8 data u4
      int s = e >> 3, u = e & 7;
      int row = s / 10, col = s % 10;
      int gy = 4 * h + row - 1, gx = col - 1;
      d = s * 10 + u;
      if (gy >= 0 && gy < 8 && gx >= 0 && gx < 8)
        v = ((b * 8 + gy) * 8 + gx) * 64 + u * 8;
    }
    csrc[k2] = v; cdst[k2] = d;
  }
  float vst[16], ist[16];
#pragma unroll
  for (int r = 0; r < 16; ++r) { vst[r] = 0.f; ist[r] = 0.f; }

  for (int t = 0; t < 16; ++t) {
    __syncthreads();                         // prior-t img readers done
    {
      const unsigned short* zt = z2bf + (size_t)t * 524288;
#pragma unroll
      for (int k2 = 0; k2 < 2; ++k2) {
        int e = tid + k2 * 256;
        if (e < 480) {
          uint4 val = {0, 0, 0, 0};
          if (csrc[k2] >= 0) val = *(const uint4*)(zt + csrc[k2]);
          imgu4[cdst[k2]] = val;
        }
      }
    }
    __syncthreads();
    f32x16 acc = {};
#pragma unroll
    for (int s9 = 0; s9 < 9; ++s9) {
      const int dy = s9 / 3, dx = s9 % 3;
      const unsigned short* ap = &img[yy + dy][xx + dx][kg * 8];
#pragma unroll
      for (int kc = 0; kc < 4; ++kc) {
        bf16x8 a = *(const bf16x8*)(ap + kc * 16);
#pragma unroll
        for (int sp = 0; sp < 3; ++sp)
          acc = mfma32(a, bw[kc][sp][s9], acc);
      }
    }
    float z[16];
#pragma unroll
    for (int r = 0; r < 16; ++r)
      z[r] = lif1(acc[r], 0.1f, vst[r], ist[r]);
    float p00 = z[0] + z[1] + z[4] + z[5];
    float p01 = z[2] + z[3] + z[6] + z[7];
    float p10 = z[8] + z[9] + z[12] + z[13];
    float p11 = z[10] + z[11] + z[14] + z[15];
    unsigned short* zo = z3t + (size_t)t * 262144 + b * 2048 + (w * 32 + lo) * 16;
    unsigned int pk0 = (unsigned int)f2bf(0.25f * p00) | ((unsigned int)f2bf(0.25f * p01) << 16);
    unsigned int pk1 = (unsigned int)f2bf(0.25f * p10) | ((unsigned int)f2bf(0.25f * p11) << 16);
    *(unsigned int*)&zo[(h * 2 + 0) * 4 + 2 * kg] = pk0;
    *(unsigned int*)&zo[(h * 2 + 1) * 4 + 2 * kg] = pk1;
  }
}

// ---------- fc1 (2048->1024) MFMA, K-split 8, B in REGS (24 frags) ----------
// grid 1024 = kb8 x nb64(16 n) x bb2; 256 thr = 4 waves (bt). LDS = 32 KB slab only.
__global__ __launch_bounds__(256) void k_fc1(const unsigned short* __restrict__ z3t,
    const float* __restrict__ wf1, float* __restrict__ P1)
{
  const int bid = blockIdx.x;
  const int kb = bid & 7, nb = (bid >> 3) & 63, bb = bid >> 9;
  const int tid = threadIdx.x;
  __shared__ __align__(16) unsigned short slab[16384];  // wl3 staging first, then A-slab
  for (int i = tid; i < 4096; i += 256) {
    int n = i >> 8, k = i & 255;
    float wv = wf1[(size_t)(nb * 16 + n) * 2048 + kb * 256 + k];
    unsigned short hi = f2bf(wv);
    float r1 = wv - bf2f(hi);
    unsigned short mid = f2bf(r1);
    unsigned short lo = f2bf(r1 - bf2f(mid));
    int off = ((k >> 5) * 4 + ((k >> 3) & 3)) * 128 + n * 8 + (k & 7);
    slab[off] = hi; slab[4096 + off] = mid; slab[8192 + off] = lo;
  }
  __syncthreads();
  const int w = tid >> 6, l = tid & 63;
  const int lg = l >> 4, ll = l & 15;
  bf16x8 bwf[8][3];
#pragma unroll
  for (int ks = 0; ks < 8; ++ks)
#pragma unroll
    for (int sp = 0; sp < 3; ++sp)
      bwf[ks][sp] = *(const bf16x8*)&slab[sp * 4096 + (ks * 4 + lg) * 128 + ll * 8];
  const int arow = w * 16 + ll;
  const int bo = bb * 64 + w * 16;

  for (int t = 0; t < 16; ++t) {
    __syncthreads();                      // prior readers of slab done
    for (int gidx = tid; gidx < 2048; gidx += 256) {
      int row = gidx >> 5, gc = gidx & 31;
      const uint4* s = (const uint4*)(z3t + (size_t)t * 262144 +
                                      ((bb * 64 + row) * 2048 + kb * 256 + gc * 8));
      ((uint4*)slab)[row * 32 + (gc ^ (row & 7))] = *s;
    }
    __syncthreads();
    f32x4 acc = {};
#pragma unroll
    for (int ks = 0; ks < 8; ++ks) {
      bf16x8 a = *(const bf16x8*)&slab[(arow * 32 + ((ks * 4 + lg) ^ (arow & 7))) * 8];
#pragma unroll
      for (int sp = 0; sp < 3; ++sp)
        acc = mfma16(a, bwf[ks][sp], acc);
    }
    float* Pt = P1 + (size_t)t * 1048576 + (size_t)kb * 131072;
#pragma unroll
    for (int r = 0; r < 4; ++r)
      Pt[(bo + 4 * lg + r) * 1024 + nb * 16 + ll] = acc[r];
  }
}

// ---------- fc1 reduce + LIF(0.1), t-loop, state in regs -> z4bf[t][b][n] ----------
__global__ __launch_bounds__(256) void k_fc1b(const float* __restrict__ P1,
    unsigned short* __restrict__ z4bf)
{
  const int site = blockIdx.x * 256 + threadIdx.x;   // 131072 = b*1024+n
  float v = 0.f, ii = 0.f;
  for (int t = 0; t < 16; ++t) {
    const float* p = P1 + (size_t)t * 1048576 + site;
    float a = 0.f;
#pragma unroll
    for (int kb = 0; kb < 8; ++kb) a += p[(size_t)kb * 131072];
    float z = lif1(a, 0.1f, v, ii);
    z4bf[(size_t)t * 131072 + site] = f2bf(z);
  }
}

// ---------- out-layer dots, parallel over (t,b): D[t][b][10] ----------
// grid 512 x 256 thr = 4 waves; wave handles one (t,b) pair.
__global__ __launch_bounds__(256) void k_dot(const unsigned short* __restrict__ z4bf,
    const float* __restrict__ wo, float* __restrict__ D)
{
  const int w = threadIdx.x >> 6, l = threadIdx.x & 63;
  const int tb = blockIdx.x * 4 + w;          // 0..2047 = t*128+b
  float zz[16];
#pragma unroll
  for (int c = 0; c < 2; ++c) {
    bf16x8 v8 = *(const bf16x8*)&z4bf[(size_t)tb * 1024 + c * 512 + l * 8];
#pragma unroll
    for (int e = 0; e < 8; ++e) zz[c * 8 + e] = bf2f((unsigned short)v8[e]);
  }
  float dot[10];
#pragma unroll
  for (int o = 0; o < 10; ++o) {
    float a = 0.f;
#pragma unroll
    for (int c = 0; c < 2; ++c) {
      const int k0 = c * 512 + l * 8;
      const float4 w0 = *(const float4*)&wo[o * 1024 + k0];
      const float4 w1 = *(const float4*)&wo[o * 1024 + k0 + 4];
      a += zz[c*8+0]*w0.x + zz[c*8+1]*w0.y + zz[c*8+2]*w0.z + zz[c*8+3]*w0.w
         + zz[c*8+4]*w1.x + zz[c*8+5]*w1.y + zz[c*8+6]*w1.z + zz[c*8+7]*w1.w;
    }
    dot[o] = a;
  }
#pragma unroll
  for (int o = 0; o < 10; ++o)
#pragma unroll
    for (int d = 32; d > 0; d >>= 1) dot[o] += __shfl_down(dot[o], d);
  if (l == 0) {
#pragma unroll
    for (int o = 0; o < 10; ++o) D[tb * 10 + o] = dot[o];
  }
}

// ---------- LI recurrence + running max over t -> out (1280 sites) ----------
__global__ __launch_bounds__(256) void k_li(const float* __restrict__ D,
    float* __restrict__ out)
{
  const int site = blockIdx.x * 256 + threadIdx.x;   // b*10+o
  if (site >= 1280) return;
  float v = 0.f, ii = 0.f, om = 0.f;
  for (int t = 0; t < 16; ++t) {
    float d = D[t * 1280 + site];
    float vn = fmaf(0.1f, ii - v, v);
    ii = fmaf(0.8f, ii, d);
    v = vn;
    om = (t == 0) ? vn : fmaxf(om, vn);
  }
  out[site] = om;
}

extern "C" void kernel_launch(void* const* d_in, const int* in_sizes, int n_in,
                              void* d_out, int out_size, void* d_ws, size_t ws_size,
                              hipStream_t stream)
{
  const float* x   = (const float*)d_in[0];   // (16,128,3,32,32)
  const float* wc1 = (const float*)d_in[1];   // (32,3,3,3)
  const float* wc2 = (const float*)d_in[2];   // (64,32,3,3)
  const float* wc3 = (const float*)d_in[3];   // (128,64,3,3)
  const float* wf1 = (const float*)d_in[4];   // (1024,2048)
  const float* wo  = (const float*)d_in[5];   // (10,1024)
  float* out = (float*)d_out;                 // (128,10)
  char* ws = (char*)d_ws;

  unsigned short* z1bf = (unsigned short*)(ws + 0);          // [16][128,16,16,32]
  unsigned short* z2bf = (unsigned short*)(ws + 33554432);   // [16][128,8,8,64]
  unsigned short* z3t  = (unsigned short*)(ws + 50331648);   // [16][128,2048]
  unsigned short* z4bf = (unsigned short*)(ws + 58720256);   // [16][128,1024]
  float* P1            = (float*)(ws + 62914560);            // [16][8][131072]
  unsigned short* wc2pk = (unsigned short*)(ws + 130023424);
  unsigned short* wc3pk = (unsigned short*)(ws + 130134016); // 221184 sh
  float* D             = (float*)(ws + 130576384);           // [16][128][10] = 81920 B

  k_pack2<<<216, 256, 0, stream>>>(wc2, wc2pk);
  k_pack3<<<864, 256, 0, stream>>>(wc3, wc3pk);

  k_conv1<<<1024, 256, 0, stream>>>(x, wc1, z1bf);
  k_conv2<<<512, 256, 0, stream>>>(z1bf, wc2pk, z2bf);
  k_conv3<<<256, 256, 0, stream>>>(z2bf, wc3pk, z3t);
  k_fc1 <<<1024, 256, 0, stream>>>(z3t, wf1, P1);
  k_fc1b<<<512, 256, 0, stream>>>(P1, z4bf);
  k_dot <<<512, 256, 0, stream>>>(z4bf, wo, D);
  k_li  <<<5, 256, 0, stream>>>(D, out);
}

// Round 22
// 263.971 us; speedup vs baseline: 2.5243x; 1.0350x over previous
//
#include <hip/hip_runtime.h>

// ConvSNN forward, T=16, B=128. One kernel per LAYER, t-loop inside, LIF state
// in REGISTERS. conv2/conv3/fc1 via MFMA bf16 with TRIPLE-split weights
// (hi+mid+lo ~= fp32 to ~2^-27 rel); activations are pooled spikes, exact bf16.
// conv3 via mfma_f32_32x32x16 (B-frags in regs, launch_bounds(256,1)).
// THIS ROUND: conv1 weights hoisted to REGISTERS (112 floats/thread) with
// __launch_bounds__(256,1) (the conv3-proven recipe; r13 spilled only because
// the default allocator cap was 128). Kills the dominant 28 b128/t LDS reload.

typedef __attribute__((ext_vector_type(8))) short bf16x8;
typedef __attribute__((ext_vector_type(4))) float f32x4;
typedef __attribute__((ext_vector_type(16))) float f32x16;

__device__ __forceinline__ unsigned short f2bf(float f) {
  unsigned int u = __float_as_uint(f);
  return (unsigned short)((u + 0x7fffu + ((u >> 16) & 1u)) >> 16);
}
__device__ __forceinline__ float bf2f(unsigned short h) {
  return __uint_as_float(((unsigned int)h) << 16);
}
__device__ __forceinline__ unsigned short split3(float wv, int sp) {
  unsigned short hi = f2bf(wv);
  float r1 = wv - bf2f(hi);
  unsigned short mid = f2bf(r1);
  if (sp == 0) return hi;
  if (sp == 1) return mid;
  return f2bf(r1 - bf2f(mid));
}
__device__ __forceinline__ float lif1(float inp, float vth, float& v, float& i) {
  float vd = fmaf(0.1f, i - v, v);
  float z = (vd > vth) ? 1.0f : 0.0f;
  v = (vd > vth) ? 0.0f : vd;
  i = fmaf(0.8f, i, inp);
  return z;
}
__device__ __forceinline__ f32x4 mfma16(bf16x8 a, bf16x8 b, f32x4 c) {
  return __builtin_amdgcn_mfma_f32_16x16x32_bf16(a, b, c, 0, 0, 0);
}
__device__ __forceinline__ f32x16 mfma32(bf16x8 a, bf16x8 b, f32x16 c) {
  return __builtin_amdgcn_mfma_f32_32x32x16_bf16(a, b, c, 0, 0, 0);
}

// ---------- one-time weight split+pack into B-fragment order ----------
// conv2 layout: [ocg 4][sp 3][dydx 9][g 4][ocl 16][j 8]  (ic = 8g+j); 55296
__global__ __launch_bounds__(256) void k_pack2(const float* __restrict__ wc2,
                                               unsigned short* __restrict__ wpk) {
  int idx = blockIdx.x * 256 + threadIdx.x;
  if (idx >= 55296) return;
  int j = idx & 7, ocl = (idx >> 3) & 15, g = (idx >> 7) & 3;
  int r = idx >> 9;                         // 0..107
  int dydx = r % 9; int q = r / 9;          // 0..11
  int sp = q % 3, ocg = q / 3;
  int oc = ocg * 16 + ocl, ic = g * 8 + j;
  wpk[idx] = split3(wc2[(oc * 32 + ic) * 9 + dydx], sp);
}
// conv3 (32x32x16 B-frag order): [ot 4][kc 4][sp 3][s9 9][kg 2][oc 32][j 8]; 221184
__global__ __launch_bounds__(256) void k_pack3(const float* __restrict__ wc3,
                                               unsigned short* __restrict__ wpk) {
  int idx = blockIdx.x * 256 + threadIdx.x;
  if (idx >= 221184) return;
  int j = idx & 7, oc = (idx >> 3) & 31, kg = (idx >> 8) & 1;
  int rr = idx >> 9;                        // 0..431
  int s9 = rr % 9; int q = rr / 9;          // 0..47
  int sp = q % 3; int q2 = q / 3;           // 0..15
  int kc = q2 & 3, ot = q2 >> 2;
  int oc_g = ot * 32 + oc, ic = kc * 16 + kg * 8 + j;
  wpk[idx] = split3(wc3[(oc_g * 64 + ic) * 9 + s9], sp);
}

// ---------- conv1 (3->32) fp32, dbuf LDS, weights in REGS, 1 barrier/t ----------
// grid 1024 = b(128) x h(2) x g(4: 8 oc); 256 thr = 128 sites x 2 sub(4 oc each).
__global__ __launch_bounds__(256, 1) void k_conv1(const float* __restrict__ x,
    const float* __restrict__ wc, unsigned short* __restrict__ z1bf)
{
  const int bid = blockIdx.x;
  const int g = bid & 3, h = (bid >> 2) & 1, b = bid >> 3;
  const int tid = threadIdx.x;
  __shared__ float xs[2][3][18][34];           // 2 x 7344 B
  __shared__ __align__(16) float wl[8][28];    // rows padded 27->28
  for (int i = tid; i < 216; i += 256) wl[i / 27][i % 27] = wc[g * 216 + i];
  int ssrc[8];
#pragma unroll
  for (int k2 = 0; k2 < 8; ++k2) {
    int i = tid + k2 * 256;
    int v = -1;
    if (i < 1836) {
      int c = i / 612, rr = i % 612;
      int row = rr / 34, col = rr % 34;
      int gy = h * 16 + row - 1, gx = col - 1;
      if (gy >= 0 && gy < 32 && gx >= 0 && gx < 32) v = c * 1024 + gy * 32 + gx;
    }
    ssrc[k2] = v;
  }
  const int site = tid >> 1, sub = tid & 1;
  const int ph = site >> 4, pw = site & 15;
  const int py = h * 8 + ph;
  float vst[4][4], ist[4][4];
#pragma unroll
  for (int jj = 0; jj < 4; ++jj)
#pragma unroll
    for (int r = 0; r < 4; ++r) { vst[jj][r] = 0.f; ist[jj][r] = 0.f; }

  float vals[8];
  float* xsf0 = &xs[0][0][0][0];
  float* xsf1 = &xs[1][0][0][0];
  {
    const float* xt0 = x + b * 3072;
#pragma unroll
    for (int k2 = 0; k2 < 8; ++k2)
      vals[k2] = (ssrc[k2] >= 0) ? xt0[ssrc[k2]] : 0.f;
#pragma unroll
    for (int k2 = 0; k2 < 8; ++k2) {
      int i = tid + k2 * 256;
      if (i < 1836) xsf0[i] = vals[k2];
    }
    const float* xt1 = x + 393216 + b * 3072;
#pragma unroll
    for (int k2 = 0; k2 < 8; ++k2)
      vals[k2] = (ssrc[k2] >= 0) ? xt1[ssrc[k2]] : 0.f;
  }
  __syncthreads();                             // wl + buf0 staged
  // hoist weights to registers ONCE (t-invariant): 4 oc x 28 floats (static idx)
  float wreg[4][28];
#pragma unroll
  for (int jj = 0; jj < 4; ++jj) {
    const float4* wrow = (const float4*)&wl[sub * 4 + jj][0];
#pragma unroll
    for (int u = 0; u < 7; ++u) *(float4*)&wreg[jj][u * 4] = wrow[u];
  }

  for (int t = 0; t < 16; ++t) {
    float* xw = (t & 1) ? xsf0 : xsf1;         // write target = buf[(t+1)&1]
    const float (*xr)[18][34] = xs[t & 1];     // read buffer
    if (t < 15) {
#pragma unroll
      for (int k2 = 0; k2 < 8; ++k2) {
        int i = tid + k2 * 256;
        if (i < 1836) xw[i] = vals[k2];
      }
    }
    if (t < 14) {
      const float* xt = x + (size_t)(t + 2) * 393216 + b * 3072;
#pragma unroll
      for (int k2 = 0; k2 < 8; ++k2)
        vals[k2] = (ssrc[k2] >= 0) ? xt[ssrc[k2]] : 0.f;
    }
    float p[3][4][4];
#pragma unroll
    for (int c = 0; c < 3; ++c)
#pragma unroll
      for (int r = 0; r < 4; ++r) {
        float2 q0 = *(const float2*)&xr[c][2 * ph + r][2 * pw];
        float2 q1 = *(const float2*)&xr[c][2 * ph + r][2 * pw + 2];
        p[c][r][0] = q0.x; p[c][r][1] = q0.y; p[c][r][2] = q1.x; p[c][r][3] = q1.y;
      }
    unsigned short zout[4];
#pragma unroll
    for (int jj = 0; jj < 4; ++jj) {
      float s00 = 0, s01 = 0, s10 = 0, s11 = 0;
#pragma unroll
      for (int c = 0; c < 3; ++c)
#pragma unroll
        for (int kh = 0; kh < 3; ++kh)
#pragma unroll
          for (int kw = 0; kw < 3; ++kw) {
            float wvv = wreg[jj][(c * 3 + kh) * 3 + kw];
            s00 = fmaf(p[c][kh][kw],     wvv, s00);
            s01 = fmaf(p[c][kh][kw+1],   wvv, s01);
            s10 = fmaf(p[c][kh+1][kw],   wvv, s10);
            s11 = fmaf(p[c][kh+1][kw+1], wvv, s11);
          }
      float z0 = lif1(s00, 0.25f, vst[jj][0], ist[jj][0]);
      float z1 = lif1(s01, 0.25f, vst[jj][1], ist[jj][1]);
      float z2 = lif1(s10, 0.25f, vst[jj][2], ist[jj][2]);
      float z3 = lif1(s11, 0.25f, vst[jj][3], ist[jj][3]);
      zout[jj] = f2bf(0.25f * (z0 + z1 + z2 + z3));
    }
    *(uint2*)&z1bf[(size_t)t * 1048576 + ((b * 16 + py) * 16 + pw) * 32 + g * 8 + sub * 4]
        = *(uint2*)zout;
    __syncthreads();                           // single barrier per t
  }
}

// ---------- conv2 (32->64) MFMA, B in REGS, dbuf img, in-register pooling ----------
// grid 512 = ocg(4: 16 oc) x b(128); 256 thr = 4 waves.
__global__ __launch_bounds__(256, 2) void k_conv2(const unsigned short* __restrict__ z1bf,
    const unsigned short* __restrict__ wpk, unsigned short* __restrict__ z2bf)
{
  const int ocg = blockIdx.x & 3, b = blockIdx.x >> 2;
  const int tid = threadIdx.x;
  __shared__ __align__(16) unsigned short img[2][18][18][40];   // 2 x 25920 B
  const int w = tid >> 6, l = tid & 63;
  const int lg = l >> 4, ll = l & 15;
  const int ry = ll >> 3, xi = ll & 7;
  bf16x8 bw[3][9];
  {
    const unsigned short* wp = wpk + ocg * 13824;
#pragma unroll
    for (int sp = 0; sp < 3; ++sp)
#pragma unroll
      for (int s9 = 0; s9 < 9; ++s9)
        bw[sp][s9] = *(const bf16x8*)(wp + ((sp * 9 + s9) * 4 + lg) * 128 + ll * 8);
  }
  uint4* imgu4 = (uint4*)&img[0][0][0][0];
  {
    uint4 zz = {0, 0, 0, 0};
    for (int e = tid; e < 1620; e += 256)
      if ((e % 5) == 4) { imgu4[e] = zz; imgu4[1620 + e] = zz; }
  }
  int csrc[6], cdst[6];
#pragma unroll
  for (int k2 = 0; k2 < 6; ++k2) {
    int e = tid + k2 * 256;
    int v = -1, d = 0;
    if (e < 1296) {
      int s = e >> 2, u = e & 3;
      int row = s / 18, col = s % 18;
      int gy = row - 1, gx = col - 1;
      d = s * 5 + u;
      if (gy >= 0 && gy < 16 && gx >= 0 && gx < 16)
        v = ((b * 16 + gy) * 16 + gx) * 32 + u * 8;
    }
    csrc[k2] = v; cdst[k2] = d;
  }
  float vst[2][2][4], ist[2][2][4];
#pragma unroll
  for (int rp = 0; rp < 2; ++rp)
#pragma unroll
    for (int ch = 0; ch < 2; ++ch)
#pragma unroll
      for (int r = 0; r < 4; ++r) { vst[rp][ch][r] = 0.f; ist[rp][ch][r] = 0.f; }

  uint4 vals[6];
  {
#pragma unroll
    for (int k2 = 0; k2 < 6; ++k2) {
      uint4 val = {0, 0, 0, 0};
      if (csrc[k2] >= 0) val = *(const uint4*)(z1bf + csrc[k2]);
      vals[k2] = val;
    }
#pragma unroll
    for (int k2 = 0; k2 < 6; ++k2) {
      int e = tid + k2 * 256;
      if (e < 1296) imgu4[cdst[k2]] = vals[k2];
    }
    const unsigned short* zt1 = z1bf + 1048576;
#pragma unroll
    for (int k2 = 0; k2 < 6; ++k2) {
      uint4 val = {0, 0, 0, 0};
      if (csrc[k2] >= 0) val = *(const uint4*)(zt1 + csrc[k2]);
      vals[k2] = val;
    }
  }
  __syncthreads();                             // buf0 staged

  for (int t = 0; t < 16; ++t) {
    const int cur = t & 1, nxt = cur ^ 1;
    if (t < 15) {
#pragma unroll
      for (int k2 = 0; k2 < 6; ++k2) {
        int e = tid + k2 * 256;
        if (e < 1296) imgu4[nxt * 1620 + cdst[k2]] = vals[k2];
      }
    }
    if (t < 14) {
      const unsigned short* zt = z1bf + (size_t)(t + 2) * 1048576;
#pragma unroll
      for (int k2 = 0; k2 < 6; ++k2) {
        uint4 val = {0, 0, 0, 0};
        if (csrc[k2] >= 0) val = *(const uint4*)(zt + csrc[k2]);
        vals[k2] = val;
      }
    }
    f32x4 acc[2][2] = {};
#pragma unroll
    for (int s9 = 0; s9 < 9; ++s9) {
      const int dy = s9 / 3, dx = s9 % 3;
      bf16x8 a[2][2];
#pragma unroll
      for (int rp = 0; rp < 2; ++rp)
#pragma unroll
        for (int ch = 0; ch < 2; ++ch)
          a[rp][ch] = *(const bf16x8*)&img[cur][4 * w + 2 * rp + ry + dy][ch * 8 + xi + dx][8 * lg];
#pragma unroll
      for (int sp = 0; sp < 3; ++sp)
#pragma unroll
        for (int rp = 0; rp < 2; ++rp)
#pragma unroll
          for (int ch = 0; ch < 2; ++ch)
            acc[rp][ch] = mfma16(a[rp][ch], bw[sp][s9], acc[rp][ch]);
    }
    float ps[2][2][2];
#pragma unroll
    for (int rp = 0; rp < 2; ++rp)
#pragma unroll
      for (int ch = 0; ch < 2; ++ch) {
        float z0 = lif1(acc[rp][ch][0], 0.2f, vst[rp][ch][0], ist[rp][ch][0]);
        float z1 = lif1(acc[rp][ch][1], 0.2f, vst[rp][ch][1], ist[rp][ch][1]);
        float z2 = lif1(acc[rp][ch][2], 0.2f, vst[rp][ch][2], ist[rp][ch][2]);
        float z3 = lif1(acc[rp][ch][3], 0.2f, vst[rp][ch][3], ist[rp][ch][3]);
        ps[rp][ch][0] = z0 + z1;
        ps[rp][ch][1] = z2 + z3;
      }
#pragma unroll
    for (int rp = 0; rp < 2; ++rp)
#pragma unroll
      for (int ch = 0; ch < 2; ++ch)
#pragma unroll
        for (int q = 0; q < 2; ++q)
          ps[rp][ch][q] += __shfl_xor(ps[rp][ch][q], 32);
    if (lg < 2) {
      const int pcb = 2 * (lg & 1);
#pragma unroll
      for (int rp = 0; rp < 2; ++rp)
#pragma unroll
        for (int ch = 0; ch < 2; ++ch)
#pragma unroll
          for (int q = 0; q < 2; ++q)
            z2bf[(size_t)t * 524288 +
                 ((b * 8 + 2 * w + rp) * 8 + ch * 4 + pcb + q) * 64 + ocg * 16 + ll]
                = f2bf(0.25f * ps[rp][ch][q]);
    }
    __syncthreads();                           // single barrier per t
  }
}

// ---------- conv3 (64->128) via mfma_32x32x16, B in REGS (108 frags) ----------
// grid 256 = h(2) x b(128); 256 thr = 4 waves (oc-tile of 32).
__global__ __launch_bounds__(256, 1) void k_conv3(const unsigned short* __restrict__ z2bf,
    const unsigned short* __restrict__ wpk, unsigned short* __restrict__ z3t)
{
  const int h = blockIdx.x & 1, b = blockIdx.x >> 1;
  const int tid = threadIdx.x;
  __shared__ __align__(16) unsigned short img[6][10][80];  // rows 4h-1..4h+4, cols -1..8
  const int w = tid >> 6, l = tid & 63;
  const int kg = l >> 5, lo = l & 31;       // A: px = lo; B: oc = lo
  const int yy = lo >> 3, xx = lo & 7;
  bf16x8 bw[4][3][9];
#pragma unroll
  for (int kc = 0; kc < 4; ++kc)
#pragma unroll
    for (int sp = 0; sp < 3; ++sp)
#pragma unroll
      for (int s9 = 0; s9 < 9; ++s9)
        bw[kc][sp][s9] = *(const bf16x8*)(wpk +
            (((((w * 4 + kc) * 3 + sp) * 9 + s9) * 2 + kg) << 8) + lo * 8);
  uint4* imgu4 = (uint4*)&img[0][0][0];
  {
    uint4 zz = {0, 0, 0, 0};
    for (int e = tid; e < 120; e += 256) {   // 60 cells x 2 pad u4
      int s = e >> 1, u = 8 + (e & 1);
      imgu4[s * 10 + u] = zz;
    }
  }
  int csrc[2], cdst[2];
#pragma unroll
  for (int k2 = 0; k2 < 2; ++k2) {
    int e = tid + k2 * 256;
    int v = -1, d = 0;
    if (e < 480) {                           // 60 cells x 8 data u4
      int s = e >> 3, u = e & 7;
      int row = s / 10, col = s % 10;
      int gy = 4 * h + row - 1, gx = col - 1;
      d = s * 10 + u;
      if (gy >= 0 && gy < 8 && gx >= 0 && gx < 8)
        v = ((b * 8 + gy) * 8 + gx) * 64 + u * 8;
    }
    csrc[k2] = v; cdst[k2] = d;
  }
  float vst[16], ist[16];
#pragma unroll
  for (int r = 0; r < 16; ++r) { vst[r] = 0.f; ist[r] = 0.f; }

  for (int t = 0; t < 16; ++t) {
    __syncthreads();                         // prior-t img readers done
    {
      const unsigned short* zt = z2bf + (size_t)t * 524288;
#pragma unroll
      for (int k2 = 0; k2 < 2; ++k2) {
        int e = tid + k2 * 256;
        if (e < 480) {
          uint4 val = {0, 0, 0, 0};
          if (csrc[k2] >= 0) val = *(const uint4*)(zt + csrc[k2]);
          imgu4[cdst[k2]] = val;
        }
      }
    }
    __syncthreads();
    f32x16 acc = {};
#pragma unroll
    for (int s9 = 0; s9 < 9; ++s9) {
      const int dy = s9 / 3, dx = s9 % 3;
      const unsigned short* ap = &img[yy + dy][xx + dx][kg * 8];
#pragma unroll
      for (int kc = 0; kc < 4; ++kc) {
        bf16x8 a = *(const bf16x8*)(ap + kc * 16);
#pragma unroll
        for (int sp = 0; sp < 3; ++sp)
          acc = mfma32(a, bw[kc][sp][s9], acc);
      }
    }
    float z[16];
#pragma unroll
    for (int r = 0; r < 16; ++r)
      z[r] = lif1(acc[r], 0.1f, vst[r], ist[r]);
    float p00 = z[0] + z[1] + z[4] + z[5];
    float p01 = z[2] + z[3] + z[6] + z[7];
    float p10 = z[8] + z[9] + z[12] + z[13];
    float p11 = z[10] + z[11] + z[14] + z[15];
    unsigned short* zo = z3t + (size_t)t * 262144 + b * 2048 + (w * 32 + lo) * 16;
    unsigned int pk0 = (unsigned int)f2bf(0.25f * p00) | ((unsigned int)f2bf(0.25f * p01) << 16);
    unsigned int pk1 = (unsigned int)f2bf(0.25f * p10) | ((unsigned int)f2bf(0.25f * p11) << 16);
    *(unsigned int*)&zo[(h * 2 + 0) * 4 + 2 * kg] = pk0;
    *(unsigned int*)&zo[(h * 2 + 1) * 4 + 2 * kg] = pk1;
  }
}

// ---------- fc1 (2048->1024) MFMA, K-split 8, B in REGS (24 frags) ----------
// grid 1024 = kb8 x nb64(16 n) x bb2; 256 thr = 4 waves (bt). LDS = 32 KB slab only.
__global__ __launch_bounds__(256) void k_fc1(const unsigned short* __restrict__ z3t,
    const float* __restrict__ wf1, float* __restrict__ P1)
{
  const int bid = blockIdx.x;
  const int kb = bid & 7, nb = (bid >> 3) & 63, bb = bid >> 9;
  const int tid = threadIdx.x;
  __shared__ __align__(16) unsigned short slab[16384];  // wl3 staging first, then A-slab
  for (int i = tid; i < 4096; i += 256) {
    int n = i >> 8, k = i & 255;
    float wv = wf1[(size_t)(nb * 16 + n) * 2048 + kb * 256 + k];
    unsigned short hi = f2bf(wv);
    float r1 = wv - bf2f(hi);
    unsigned short mid = f2bf(r1);
    unsigned short lo = f2bf(r1 - bf2f(mid));
    int off = ((k >> 5) * 4 + ((k >> 3) & 3)) * 128 + n * 8 + (k & 7);
    slab[off] = hi; slab[4096 + off] = mid; slab[8192 + off] = lo;
  }
  __syncthreads();
  const int w = tid >> 6, l = tid & 63;
  const int lg = l >> 4, ll = l & 15;
  bf16x8 bwf[8][3];
#pragma unroll
  for (int ks = 0; ks < 8; ++ks)
#pragma unroll
    for (int sp = 0; sp < 3; ++sp)
      bwf[ks][sp] = *(const bf16x8*)&slab[sp * 4096 + (ks * 4 + lg) * 128 + ll * 8];
  const int arow = w * 16 + ll;
  const int bo = bb * 64 + w * 16;

  for (int t = 0; t < 16; ++t) {
    __syncthreads();                      // prior readers of slab done
    for (int gidx = tid; gidx < 2048; gidx += 256) {
      int row = gidx >> 5, gc = gidx & 31;
      const uint4* s = (const uint4*)(z3t + (size_t)t * 262144 +
                                      ((bb * 64 + row) * 2048 + kb * 256 + gc * 8));
      ((uint4*)slab)[row * 32 + (gc ^ (row & 7))] = *s;
    }
    __syncthreads();
    f32x4 acc = {};
#pragma unroll
    for (int ks = 0; ks < 8; ++ks) {
      bf16x8 a = *(const bf16x8*)&slab[(arow * 32 + ((ks * 4 + lg) ^ (arow & 7))) * 8];
#pragma unroll
      for (int sp = 0; sp < 3; ++sp)
        acc = mfma16(a, bwf[ks][sp], acc);
    }
    float* Pt = P1 + (size_t)t * 1048576 + (size_t)kb * 131072;
#pragma unroll
    for (int r = 0; r < 4; ++r)
      Pt[(bo + 4 * lg + r) * 1024 + nb * 16 + ll] = acc[r];
  }
}

// ---------- fc1 reduce + LIF(0.1), t-loop, state in regs -> z4bf[t][b][n] ----------
__global__ __launch_bounds__(256) void k_fc1b(const float* __restrict__ P1,
    unsigned short* __restrict__ z4bf)
{
  const int site = blockIdx.x * 256 + threadIdx.x;   // 131072 = b*1024+n
  float v = 0.f, ii = 0.f;
  for (int t = 0; t < 16; ++t) {
    const float* p = P1 + (size_t)t * 1048576 + site;
    float a = 0.f;
#pragma unroll
    for (int kb = 0; kb < 8; ++kb) a += p[(size_t)kb * 131072];
    float z = lif1(a, 0.1f, v, ii);
    z4bf[(size_t)t * 131072 + site] = f2bf(z);
  }
}

// ---------- out-layer dots, parallel over (t,b): D[t][b][10] ----------
__global__ __launch_bounds__(256) void k_dot(const unsigned short* __restrict__ z4bf,
    const float* __restrict__ wo, float* __restrict__ D)
{
  const int w = threadIdx.x >> 6, l = threadIdx.x & 63;
  const int tb = blockIdx.x * 4 + w;          // 0..2047 = t*128+b
  float zz[16];
#pragma unroll
  for (int c = 0; c < 2; ++c) {
    bf16x8 v8 = *(const bf16x8*)&z4bf[(size_t)tb * 1024 + c * 512 + l * 8];
#pragma unroll
    for (int e = 0; e < 8; ++e) zz[c * 8 + e] = bf2f((unsigned short)v8[e]);
  }
  float dot[10];
#pragma unroll
  for (int o = 0; o < 10; ++o) {
    float a = 0.f;
#pragma unroll
    for (int c = 0; c < 2; ++c) {
      const int k0 = c * 512 + l * 8;
      const float4 w0 = *(const float4*)&wo[o * 1024 + k0];
      const float4 w1 = *(const float4*)&wo[o * 1024 + k0 + 4];
      a += zz[c*8+0]*w0.x + zz[c*8+1]*w0.y + zz[c*8+2]*w0.z + zz[c*8+3]*w0.w
         + zz[c*8+4]*w1.x + zz[c*8+5]*w1.y + zz[c*8+6]*w1.z + zz[c*8+7]*w1.w;
    }
    dot[o] = a;
  }
#pragma unroll
  for (int o = 0; o < 10; ++o)
#pragma unroll
    for (int d = 32; d > 0; d >>= 1) dot[o] += __shfl_down(dot[o], d);
  if (l == 0) {
#pragma unroll
    for (int o = 0; o < 10; ++o) D[tb * 10 + o] = dot[o];
  }
}

// ---------- LI recurrence + running max over t -> out (1280 sites) ----------
__global__ __launch_bounds__(256) void k_li(const float* __restrict__ D,
    float* __restrict__ out)
{
  const int site = blockIdx.x * 256 + threadIdx.x;   // b*10+o
  if (site >= 1280) return;
  float v = 0.f, ii = 0.f, om = 0.f;
  for (int t = 0; t < 16; ++t) {
    float d = D[t * 1280 + site];
    float vn = fmaf(0.1f, ii - v, v);
    ii = fmaf(0.8f, ii, d);
    v = vn;
    om = (t == 0) ? vn : fmaxf(om, vn);
  }
  out[site] = om;
}

extern "C" void kernel_launch(void* const* d_in, const int* in_sizes, int n_in,
                              void* d_out, int out_size, void* d_ws, size_t ws_size,
                              hipStream_t stream)
{
  const float* x   = (const float*)d_in[0];   // (16,128,3,32,32)
  const float* wc1 = (const float*)d_in[1];   // (32,3,3,3)
  const float* wc2 = (const float*)d_in[2];   // (64,32,3,3)
  const float* wc3 = (const float*)d_in[3];   // (128,64,3,3)
  const float* wf1 = (const float*)d_in[4];   // (1024,2048)
  const float* wo  = (const float*)d_in[5];   // (10,1024)
  float* out = (float*)d_out;                 // (128,10)
  char* ws = (char*)d_ws;

  unsigned short* z1bf = (unsigned short*)(ws + 0);          // [16][128,16,16,32]
  unsigned short* z2bf = (unsigned short*)(ws + 33554432);   // [16][128,8,8,64]
  unsigned short* z3t  = (unsigned short*)(ws + 50331648);   // [16][128,2048]
  unsigned short* z4bf = (unsigned short*)(ws + 58720256);   // [16][128,1024]
  float* P1            = (float*)(ws + 62914560);            // [16][8][131072]
  unsigned short* wc2pk = (unsigned short*)(ws + 130023424);
  unsigned short* wc3pk = (unsigned short*)(ws + 130134016); // 221184 sh
  float* D             = (float*)(ws + 130576384);           // [16][128][10]

  k_pack2<<<216, 256, 0, stream>>>(wc2, wc2pk);
  k_pack3<<<864, 256, 0, stream>>>(wc3, wc3pk);

  k_conv1<<<1024, 256, 0, stream>>>(x, wc1, z1bf);
  k_conv2<<<512, 256, 0, stream>>>(z1bf, wc2pk, z2bf);
  k_conv3<<<256, 256, 0, stream>>>(z2bf, wc3pk, z3t);
  k_fc1 <<<1024, 256, 0, stream>>>(z3t, wf1, P1);
  k_fc1b<<<512, 256, 0, stream>>>(P1, z4bf);
  k_dot <<<512, 256, 0, stream>>>(z4bf, wo, D);
  k_li  <<<5, 256, 0, stream>>>(D, out);
}